// Round 19
// baseline (309.912 us; speedup 1.0000x reference)
//
#include <hip/hip_runtime.h>
#include <hip/hip_fp16.h>

constexpr int kN  = 50000;
constexpr int kE  = 400000;
constexpr int kHC = 128;
constexpr int kED = 32;
constexpr int kL  = 2;
constexpr int kScanB = (kN + 255) / 256;   // 196
constexpr int kProjBlocks = 512;           // persistent: 2 per CU
constexpr int kTiles = (kN + 31) / 32;     // 1563
constexpr int kKVB = 384;                  // bytes per kv row: 128 fp8 k + 256 fp16 v
#define EPS_LN 1e-5f
#define NEG_SLOPE 0.01f
#define RSQRT_C 0.17677669529663687f  // 1/sqrt(32)

using half8 = __attribute__((ext_vector_type(8))) _Float16;
using half4 = __attribute__((ext_vector_type(4))) _Float16;
using h2    = __attribute__((ext_vector_type(2))) _Float16;
using f32x4 = __attribute__((ext_vector_type(4))) float;

#if __has_builtin(__builtin_amdgcn_fdot2)
#define FDOT2(a, b, c) __builtin_amdgcn_fdot2((a), (b), (c), false)
#else
#define FDOT2(a, b, c) (fmaf((float)(a)[0], (float)(b)[0], \
                        fmaf((float)(a)[1], (float)(b)[1], (c))))
#endif

// ---------------- Weight transpose+convert: Wt[mat][n][k] fp16 --------------
__global__ __launch_bounds__(256) void wt_kernel(
    const float* __restrict__ Wq, const float* __restrict__ Wk,
    const float* __restrict__ Wv, const float* __restrict__ Ws,
    _Float16* __restrict__ Wt)
{
    const int g = blockIdx.x * 256 + threadIdx.x;   // 8192 total
    const int n  = g & 127;
    const int kc = (g >> 7) & 15;
    const int mat = g >> 11;
    const float* W = mat == 0 ? Wq : mat == 1 ? Wk : mat == 2 ? Wv : Ws;
    _Float16* dst = Wt + ((size_t)mat * 128 + n) * 128 + kc * 8;
#pragma unroll
    for (int i = 0; i < 8; i++) dst[i] = (_Float16)W[(kc * 8 + i) * kHC + n];
}

// ---------------- We -> fp16 copy (once per layer) --------------------------
__global__ __launch_bounds__(256) void we16_kernel(
    const float* __restrict__ We, _Float16* __restrict__ We16)
{
    const int g = blockIdx.x * 256 + threadIdx.x;   // 4096
    if (g < kED * kHC) We16[g] = (_Float16)We[g];
}

// ---------------- Persistent MFMA projection --------------------------------
// outputs: q16 [n][128], kv8 [n][384B] (k fp8 | v fp16), xr16 [n][128]
template<bool FP16IN>
__global__ __launch_bounds__(256, 2) void proj_mfma_kernel(
    const void* __restrict__ hin_, const _Float16* __restrict__ Wt,
    const float* __restrict__ bq, const float* __restrict__ bk,
    const float* __restrict__ bv, const float* __restrict__ bs,
    _Float16* __restrict__ q16, unsigned char* __restrict__ kv8,
    _Float16* __restrict__ xr16)
{
    __shared__ _Float16 lds_a[4096];          // [mt][ks][lane][8] frag-linear
    __shared__ _Float16 lds_o[4][32 * 132];   // repack staging, stride 132
    const int t = threadIdx.x;
    const int w = t >> 6;        // wave id = matrix id (0:q 1:k 2:v 3:skip)
    const int lane = t & 63;
    const int nrow = lane & 15;
    const int kc4  = (lane >> 4) * 4;

    half8 bf[32];
    {
        const _Float16* wtm = Wt + (size_t)w * 128 * 128;
#pragma unroll
        for (int ks = 0; ks < 4; ks++)
#pragma unroll
            for (int nt = 0; nt < 8; nt++)
                bf[ks * 8 + nt] = *(const half8*)
                    &wtm[(size_t)(nt * 16 + nrow) * 128 + ks * 32 + (lane >> 4) * 8];
    }

    const int sr  = t >> 3;
    const int sk0 = (t & 7) * 16;
    const int smt = sr >> 4;
    const int sl15 = sr & 15;

    float4 f[4];
    half8 hh[2];

    auto stage_to_regs = [&](int tile) {
        const int row = tile * 32 + sr;
        if (row < kN) {
            if constexpr (FP16IN) {
                const _Float16* src = (const _Float16*)hin_ + (size_t)row * kHC + sk0;
                hh[0] = *(const half8*)&src[0];
                hh[1] = *(const half8*)&src[8];
            } else {
                const float4* src = (const float4*)((const float*)hin_ + (size_t)row * kHC + sk0);
                f[0] = src[0]; f[1] = src[1]; f[2] = src[2]; f[3] = src[3];
            }
        } else {
            if constexpr (FP16IN) {
                hh[0] = half8{0, 0, 0, 0, 0, 0, 0, 0};
                hh[1] = half8{0, 0, 0, 0, 0, 0, 0, 0};
            } else {
                f[0] = f[1] = f[2] = f[3] = make_float4(0.f, 0.f, 0.f, 0.f);
            }
        }
    };

    auto regs_to_lds = [&]() {
        half8 h0, h1;
        if constexpr (FP16IN) {
            h0 = hh[0]; h1 = hh[1];
        } else {
            h0[0] = (_Float16)f[0].x; h0[1] = (_Float16)f[0].y;
            h0[2] = (_Float16)f[0].z; h0[3] = (_Float16)f[0].w;
            h0[4] = (_Float16)f[1].x; h0[5] = (_Float16)f[1].y;
            h0[6] = (_Float16)f[1].z; h0[7] = (_Float16)f[1].w;
            h1[0] = (_Float16)f[2].x; h1[1] = (_Float16)f[2].y;
            h1[2] = (_Float16)f[2].z; h1[3] = (_Float16)f[2].w;
            h1[4] = (_Float16)f[3].x; h1[5] = (_Float16)f[3].y;
            h1[6] = (_Float16)f[3].z; h1[7] = (_Float16)f[3].w;
        }
#pragma unroll
        for (int g = 0; g < 2; g++) {
            const int k  = sk0 + g * 8;
            const int ks = k >> 5;
            const int kc = (k >> 3) & 3;
            *(half8*)&lds_a[(((smt * 4 + ks) * 64) + kc * 16 + sl15) * 8] = g ? h1 : h0;
        }
    };

    const float* biasp = (w == 0) ? bq : (w == 1) ? bk : (w == 2) ? bv : bs;
    float bb[8];
#pragma unroll
    for (int nt = 0; nt < 8; nt++) bb[nt] = biasp[nt * 16 + nrow];

    int tile = blockIdx.x;
    stage_to_regs(tile);

    for (;;) {
        __syncthreads();
        regs_to_lds();
        __syncthreads();

        const int next = tile + kProjBlocks;
        const bool more = next < kTiles;
        if (more) stage_to_regs(next);

        f32x4 acc[2][8];
        const f32x4 z = {0.f, 0.f, 0.f, 0.f};
#pragma unroll
        for (int mt = 0; mt < 2; mt++)
#pragma unroll
            for (int nt = 0; nt < 8; nt++) acc[mt][nt] = z;

#pragma unroll
        for (int ks = 0; ks < 4; ks++) {
            const half8 a0 = *(const half8*)&lds_a[((0 * 4 + ks) * 64 + lane) * 8];
            const half8 a1 = *(const half8*)&lds_a[((1 * 4 + ks) * 64 + lane) * 8];
#pragma unroll
            for (int nt = 0; nt < 8; nt++) {
                acc[0][nt] = __builtin_amdgcn_mfma_f32_16x16x32_f16(a0, bf[ks * 8 + nt], acc[0][nt], 0, 0, 0);
                acc[1][nt] = __builtin_amdgcn_mfma_f32_16x16x32_f16(a1, bf[ks * 8 + nt], acc[1][nt], 0, 0, 0);
            }
        }

#pragma unroll
        for (int nt = 0; nt < 8; nt++) {
#pragma unroll
            for (int mt = 0; mt < 2; mt++)
#pragma unroll
                for (int r = 0; r < 4; r++)
                    lds_o[w][(mt * 16 + kc4 + r) * 132 + nt * 16 + nrow] =
                        (_Float16)(acc[mt][nt][r] + bb[nt]);
        }
        __syncthreads();

        const int grow = tile * 32 + sr;
        if (grow < kN) {
            {   // q
                const _Float16* s = &lds_o[0][sr * 132 + sk0];
                _Float16* d = q16 + (size_t)grow * kHC + sk0;
#pragma unroll
                for (int i = 0; i < 4; i++)
                    *(half4*)&d[i * 4] = *(const half4*)&s[i * 4];
            }
            {   // k fp8: row bytes [0,128), channel i at byte i
                const _Float16* sk = &lds_o[1][sr * 132 + sk0];
                unsigned int w4[4];
#pragma unroll
                for (int p = 0; p < 4; p++) {
                    unsigned int wd = 0;
                    wd = __builtin_amdgcn_cvt_pk_fp8_f32(
                        (float)sk[4 * p], (float)sk[4 * p + 1], wd, false);
                    wd = __builtin_amdgcn_cvt_pk_fp8_f32(
                        (float)sk[4 * p + 2], (float)sk[4 * p + 3], wd, true);
                    w4[p] = wd;
                }
                *(uint4*)(kv8 + (size_t)grow * kKVB + sk0) =
                    make_uint4(w4[0], w4[1], w4[2], w4[3]);
            }
            {   // v fp16: row bytes [128,384), channel i at 128 + 2i
                const _Float16* sv = &lds_o[2][sr * 132 + sk0];
                _Float16* d = (_Float16*)(kv8 + (size_t)grow * kKVB + 128) + sk0;
                *(half8*)&d[0] = *(const half8*)&sv[0];
                *(half8*)&d[8] = *(const half8*)&sv[8];
            }
            {   // xr
                const _Float16* s = &lds_o[3][sr * 132 + sk0];
                _Float16* d = xr16 + (size_t)grow * kHC + sk0;
#pragma unroll
                for (int i = 0; i < 4; i++)
                    *(half4*)&d[i * 4] = *(const half4*)&s[i * 4];
            }
        }

        if (!more) break;
        tile = next;
    }
}

// ---------------- qeW: register-blocked, 32 nodes per block -----------------
constexpr int kQewNPB = 32;
__global__ __launch_bounds__(256) void qew_kernel(
    const __half* __restrict__ q16, const float* __restrict__ We,
    __half* __restrict__ qeW)
{
    const int t = threadIdx.x;
    const int o = t & 127;       // output index = h*32 + j
    const int h = o >> 5;
    const int j = o & 31;
    const int nd = t >> 7;

    float we[32];
    const float2* wrow = (const float2*)&We[j * kHC + h * 32];
#pragma unroll
    for (int i = 0; i < 16; i++) {
        const float2 w = wrow[i];
        we[2 * i] = w.x; we[2 * i + 1] = w.y;
    }

    const int n0 = blockIdx.x * kQewNPB;
    for (int i = nd; i < kQewNPB; i += 2) {
        const int n = n0 + i;
        if (n >= kN) break;
        const __half2* qrow = (const __half2*)&q16[(size_t)n * kHC + h * 32];
        float s = 0.f;
#pragma unroll
        for (int ii = 0; ii < 16; ii++) {
            const float2 qf = __half22float2(qrow[ii]);
            s = fmaf(qf.x, we[2 * ii], s);
            s = fmaf(qf.y, we[2 * ii + 1], s);
        }
        qeW[(size_t)n * kHC + o] = __float2half(s);
    }
}

// ---------------- qb[n,h] = sum_{c in h} q[n,c]*be[c] -----------------------
__global__ __launch_bounds__(256) void qb_kernel(
    const __half* __restrict__ q16, const float* __restrict__ be,
    float* __restrict__ qb)
{
    const int g = blockIdx.x * 256 + threadIdx.x;   // n*4 + h
    if (g >= kN * 4) return;
    const int n = g >> 2, h = g & 3;
    const __half2* qrow = (const __half2*)&q16[(size_t)n * kHC + h * 32];
    const float2* brow = (const float2*)&be[h * 32];
    float s = 0.f;
#pragma unroll
    for (int i = 0; i < 16; i++) {
        const float2 qf = __half22float2(qrow[i]);
        const float2 bf = brow[i];
        s = fmaf(qf.x, bf.x, s);
        s = fmaf(qf.y, bf.y, s);
    }
    qb[g] = s;
}

// ---------------- CSR build (once per call) ---------------------------------
__global__ __launch_bounds__(256) void hist_kernel(
    const int* __restrict__ dstI, int* __restrict__ deg)
{
    const int e = blockIdx.x * 256 + threadIdx.x;
    if (e < kE) atomicAdd(&deg[dstI[e]], 1);
}

__global__ __launch_bounds__(256) void scanA_kernel(
    const int* __restrict__ deg, int* __restrict__ locInc, int* __restrict__ blockSum)
{
    __shared__ int sm[256];
    const int t = threadIdx.x;
    const int i = blockIdx.x * 256 + t;
    sm[t] = (i < kN) ? deg[i] : 0;
    __syncthreads();
    for (int off = 1; off < 256; off <<= 1) {
        const int x = (t >= off) ? sm[t - off] : 0;
        __syncthreads();
        sm[t] += x;
        __syncthreads();
    }
    if (i < kN) locInc[i] = sm[t];
    if (t == 255) blockSum[blockIdx.x] = sm[255];
}

__global__ __launch_bounds__(256) void scanC_kernel(
    const int* __restrict__ deg, const int* __restrict__ locInc,
    const int* __restrict__ blockSum,
    int* __restrict__ rowptr, int* __restrict__ cursor)
{
    __shared__ int sm[256];
    const int t = threadIdx.x;
    const int b = blockIdx.x;
    sm[t] = (t < b) ? blockSum[t] : 0;   // b <= 195 < 256
    __syncthreads();
    for (int s = 128; s > 0; s >>= 1) {
        if (t < s) sm[t] += sm[t + s];
        __syncthreads();
    }
    const int off = sm[0];
    const int i = b * 256 + t;
    if (i < kN) {
        const int inc = locInc[i];
        const int excl = off + inc - deg[i];
        rowptr[i] = excl;
        cursor[i] = excl;
        if (i == kN - 1) rowptr[kN] = off + inc;
    }
}

__global__ __launch_bounds__(256) void scatter_kernel(
    const int* __restrict__ srcI, const int* __restrict__ dstI,
    int* __restrict__ cursor, int* __restrict__ esrc, int* __restrict__ eidx)
{
    const int e = blockIdx.x * 256 + threadIdx.x;
    if (e >= kE) return;
    const int d = dstI[e];
    const int pos = atomicAdd(&cursor[d], 1);
    esrc[pos] = srcI[e];
    eidx[pos] = e;
}

// ---------------- ea -> CSR-order fp16 copy (once per call) -----------------
__global__ __launch_bounds__(256) void ea_csr_kernel(
    const float* __restrict__ ea, const int* __restrict__ eidx,
    __half* __restrict__ eacsr)
{
    const int g = blockIdx.x * 256 + threadIdx.x;   // kE*16 threads
    if (g >= kE * 16) return;
    const int jj = g >> 4;
    const int li = g & 15;
    const int eid = eidx[jj];
    const float2 ea2 = *(const float2*)&ea[(size_t)eid * kED + 2 * li];
    *(__half2*)&eacsr[(size_t)jj * kED + 2 * li] = __floats2half2_rn(ea2.x, ea2.y);
}

// ---------------- Fused node pass: 2 edges/wave, 4 channels/lane ------------
// lanes 0-31 = edge A, lanes 32-63 = edge B; 8-lane group = head.
#define PROCESS_PAIRS(U, PRED)                                               \
    {                                                                        \
        int idxv[U]; int sv[U];                                              \
        _Pragma("unroll")                                                    \
        for (int u = 0; u < U; u++) {                                        \
            idxv[u] = jj + 2 * u + half;                                     \
            if (PRED && idxv[u] >= endp) idxv[u] = beg;                      \
            sv[u] = esrc[idxv[u]];                                           \
        }                                                                    \
        unsigned int kw[U]; h2 v0[U], v1[U], e0[U], e1[U];                   \
        _Pragma("unroll")                                                    \
        for (int u = 0; u < U; u++) {                                        \
            const unsigned char* row = kv8 + (size_t)sv[u] * kKVB;           \
            kw[u] = *(const unsigned int*)(row + c4);                        \
            const _Float16* vp = (const _Float16*)(row + 128) + c4;          \
            v0[u] = *(const h2*)vp;  v1[u] = *(const h2*)(vp + 2);           \
            const _Float16* ep = eacsr + (size_t)idxv[u] * kED + lg4;        \
            e0[u] = *(const h2*)ep;  e1[u] = *(const h2*)(ep + 2);           \
        }                                                                    \
        float p[U];                                                          \
        _Pragma("unroll")                                                    \
        for (int u = 0; u < U; u++) {                                        \
            p[u] = qf[0] * __builtin_amdgcn_cvt_f32_fp8(kw[u], 0)            \
                 + qf[1] * __builtin_amdgcn_cvt_f32_fp8(kw[u], 1)            \
                 + qf[2] * __builtin_amdgcn_cvt_f32_fp8(kw[u], 2)            \
                 + qf[3] * __builtin_amdgcn_cvt_f32_fp8(kw[u], 3);           \
            p[u] = FDOT2(qwh0, e0[u], p[u]);                                 \
            p[u] = FDOT2(qwh1, e1[u], p[u]);                                 \
        }                                                                    \
        _Pragma("unroll")                                                    \
        for (int m = 1; m <= 4; m <<= 1) {                                   \
            _Pragma("unroll")                                                \
            for (int u = 0; u < U; u++) p[u] += __shfl_xor(p[u], m);         \
        }                                                                    \
        _Pragma("unroll")                                                    \
        for (int u = 0; u < U; u++) {                                        \
            float a = __expf((p[u] + qbv) * RSQRT_C);                        \
            if (PRED && (jj + 2 * u + half >= endp)) a = 0.f;                \
            den += a;                                                        \
            acc[0] = fmaf((float)v0[u][0], a, acc[0]);                       \
            acc[1] = fmaf((float)v0[u][1], a, acc[1]);                       \
            acc[2] = fmaf((float)v1[u][0], a, acc[2]);                       \
            acc[3] = fmaf((float)v1[u][1], a, acc[3]);                       \
            t4[0] = fmaf((float)e0[u][0], a, t4[0]);                         \
            t4[1] = fmaf((float)e0[u][1], a, t4[1]);                         \
            t4[2] = fmaf((float)e1[u][0], a, t4[2]);                         \
            t4[3] = fmaf((float)e1[u][1], a, t4[3]);                         \
        }                                                                    \
    }

template<bool LAST>
__global__ __launch_bounds__(128) void node_kernel(
    const _Float16* __restrict__ q16, const __half* __restrict__ qeW,
    const float* __restrict__ qb, const _Float16* __restrict__ eacsr,
    const unsigned char* __restrict__ kv8,
    const int* __restrict__ rowptr, const int* __restrict__ esrc,
    const _Float16* __restrict__ We16, const float* __restrict__ be,
    const __half* __restrict__ xr16, const float* __restrict__ Wb,
    const float* __restrict__ lnw, const float* __restrict__ lnb,
    void* __restrict__ hout)
{
    __shared__ __half wes[kED * kHC];   // 8 KB
    const int t = threadIdx.x;
    {
        float4* d4 = (float4*)wes;
        const float4* s4 = (const float4*)We16;
#pragma unroll
        for (int i = 0; i < 4; i++) d4[t + 128 * i] = s4[t + 128 * i];
    }
    __syncthreads();

    const int n = blockIdx.x * 2 + (t >> 6);   // kN % 2 == 0
    const int lane = t & 63;
    const int hl   = lane & 31;        // lane within half
    const int half = lane >> 5;        // which edge of the pair
    const int hd   = hl >> 3;          // head
    const int lg   = hl & 7;           // lane within 8-group
    const int c4   = hd * 32 + lg * 4; // 4-channel base
    const int lg4  = lg * 4;

    // per-node invariants
    float qf[4];
    h2 qwh0, qwh1;
    {
        const h2 qa = *(const h2*)&q16[n * kHC + c4];
        const h2 qbx = *(const h2*)&q16[n * kHC + c4 + 2];
        qf[0] = (float)qa[0];  qf[1] = (float)qa[1];
        qf[2] = (float)qbx[0]; qf[3] = (float)qbx[1];
        const _Float16* qw = (const _Float16*)qeW + n * kHC + c4;
        qwh0 = *(const h2*)qw;
        qwh1 = *(const h2*)(qw + 2);
    }
    const float qbv = qb[n * 4 + hd];

    float acc[4] = {0.f, 0.f, 0.f, 0.f};
    float t4[4]  = {0.f, 0.f, 0.f, 0.f};
    float den = 0.f;
    const int beg = rowptr[n], endp = rowptr[n + 1];

    int jj = beg;
    for (; jj + 8 <= endp; jj += 8) PROCESS_PAIRS(4, 0)
    for (; jj + 4 <= endp; jj += 4) PROCESS_PAIRS(2, 0)
    for (; jj < endp; jj += 2)      PROCESS_PAIRS(1, 1)

    // combine the two halves (each accumulated its own edges)
    den += __shfl_xor(den, 32);
#pragma unroll
    for (int i = 0; i < 4; i++) {
        acc[i] += __shfl_xor(acc[i], 32);
        t4[i]  += __shfl_xor(t4[i], 32);
    }

    const float invd = 1.f / (den + 1e-16f);
    float o[4], tn[4];
#pragma unroll
    for (int i = 0; i < 4; i++) { o[i] = acc[i] * invd; tn[i] = t4[i] * invd; }

    // emb contribution: o[c] += sum_j T[h,j] * We[j,c]  (+ be[c])
    const int gb = (lane & 32) | (hd * 8);
#pragma unroll
    for (int jo = 0; jo < 8; jo++) {
        float Tv[4];
#pragma unroll
        for (int ji = 0; ji < 4; ji++) Tv[ji] = __shfl(tn[ji], gb | jo);
#pragma unroll
        for (int ji = 0; ji < 4; ji++) {
            const int j = jo * 4 + ji;
            const float2 wA = __half22float2(*(const __half2*)&wes[j * kHC + c4]);
            const float2 wB = __half22float2(*(const __half2*)&wes[j * kHC + c4 + 2]);
            o[0] = fmaf(Tv[ji], wA.x, o[0]);
            o[1] = fmaf(Tv[ji], wA.y, o[1]);
            o[2] = fmaf(Tv[ji], wB.x, o[2]);
            o[3] = fmaf(Tv[ji], wB.y, o[3]);
        }
    }
#pragma unroll
    for (int i = 0; i < 4; i++) o[i] += be[c4 + i];

    // beta-gated skip + LN + LeakyReLU (4 channels per lane, halves duplicate)
    float r[4];
    {
        const float2 rA = __half22float2(*(const __half2*)&xr16[(size_t)n * kHC + c4]);
        const float2 rB = __half22float2(*(const __half2*)&xr16[(size_t)n * kHC + c4 + 2]);
        r[0] = rA.x; r[1] = rA.y; r[2] = rB.x; r[3] = rB.y;
    }
    float z = 0.f;
#pragma unroll
    for (int i = 0; i < 4; i++) {
        z += o[i] * Wb[c4 + i] + r[i] * Wb[kHC + c4 + i]
           + (o[i] - r[i]) * Wb[2 * kHC + c4 + i];
    }
#pragma unroll
    for (int m = 1; m < 32; m <<= 1) z += __shfl_xor(z, m);
    const float beta = 1.f / (1.f + __expf(-z));

    float gv[4];
    float sm = 0.f, sq = 0.f;
#pragma unroll
    for (int i = 0; i < 4; i++) {
        gv[i] = beta * r[i] + (1.f - beta) * o[i];
        sm += gv[i];
        sq += gv[i] * gv[i];
    }
#pragma unroll
    for (int m = 1; m < 32; m <<= 1) {
        sm += __shfl_xor(sm, m);
        sq += __shfl_xor(sq, m);
    }
    const float mu  = sm * (1.f / kHC);
    const float var = sq * (1.f / kHC) - mu * mu;
    const float inv = rsqrtf(var + EPS_LN);

    float y[4];
#pragma unroll
    for (int i = 0; i < 4; i++) {
        float yy = (gv[i] - mu) * inv * lnw[c4 + i] + lnb[c4 + i];
        y[i] = yy > 0.f ? yy : NEG_SLOPE * yy;
    }
    if (half == 0) {
        if constexpr (LAST) {
            *(float4*)&((float*)hout)[(size_t)n * kHC + c4] =
                make_float4(y[0], y[1], y[2], y[3]);
        } else {
            half4 hv;
            hv[0] = (_Float16)y[0]; hv[1] = (_Float16)y[1];
            hv[2] = (_Float16)y[2]; hv[3] = (_Float16)y[3];
            *(half4*)&((__half*)hout)[(size_t)n * kHC + c4] = hv;
        }
    }
}

extern "C" void kernel_launch(void* const* d_in, const int* in_sizes, int n_in,
                              void* d_out, int out_size, void* d_ws, size_t ws_size,
                              hipStream_t stream)
{
    const float* x   = (const float*)d_in[0];
    const int*   ei  = (const int*)d_in[1];
    const float* ea  = (const float*)d_in[2];
    const float* Wq  = (const float*)d_in[3];
    const float* bq  = (const float*)d_in[4];
    const float* Wk  = (const float*)d_in[5];
    const float* bk  = (const float*)d_in[6];
    const float* Wv  = (const float*)d_in[7];
    const float* bv  = (const float*)d_in[8];
    const float* We  = (const float*)d_in[9];
    const float* be  = (const float*)d_in[10];
    const float* Wsk = (const float*)d_in[11];
    const float* bsk = (const float*)d_in[12];
    const float* Wb  = (const float*)d_in[13];
    const float* lnw = (const float*)d_in[14];
    const float* lnb = (const float*)d_in[15];
    float* out = (float*)d_out;

    const int* srcI = ei;
    const int* dstI = ei + kE;

    // ---- workspace layout (~95 MB) ----
    __half* q16  = (__half*)d_ws;
    unsigned char* kv8 = (unsigned char*)(q16 + (size_t)kN * kHC);  // [n][384B]
    __half* qeW  = (__half*)(kv8 + (size_t)kN * kKVB);
    __half* xr16 = qeW + (size_t)kN * kHC;
    __half* h16  = xr16 + (size_t)kN * kHC;
    float*  qb   = (float*)(h16 + (size_t)kN * kHC);
    int* deg     = (int*)(qb + (size_t)kN * 4);
    int* rowptr  = deg + kN;
    int* cursor  = rowptr + kN + 1;
    int* esrc    = cursor + kN;
    int* eidx    = esrc + kE;
    __half* eacs = (__half*)(eidx + kE);
    _Float16* Wt = (_Float16*)(eacs + (size_t)kE * kED);   // 128 KB
    _Float16* We16 = Wt + 4 * 128 * 128;                   // 8 KB
    int* locInc  = (int*)(We16 + kED * kHC);
    int* blockSum = locInc + kN;

    // ---- CSR build (edge_index constant across layers) ----
    hipMemsetAsync(deg, 0, (size_t)kN * sizeof(int), stream);
    hist_kernel<<<(kE + 255) / 256, 256, 0, stream>>>(dstI, deg);
    scanA_kernel<<<kScanB, 256, 0, stream>>>(deg, locInc, blockSum);
    scanC_kernel<<<kScanB, 256, 0, stream>>>(deg, locInc, blockSum, rowptr, cursor);
    scatter_kernel<<<(kE + 255) / 256, 256, 0, stream>>>(srcI, dstI, cursor, esrc, eidx);
    ea_csr_kernel<<<(kE * 16 + 255) / 256, 256, 0, stream>>>(ea, eidx, eacs);

    for (int l = 0; l < kL; l++) {
        wt_kernel<<<32, 256, 0, stream>>>(
            Wq + (size_t)l * kHC * kHC, Wk + (size_t)l * kHC * kHC,
            Wv + (size_t)l * kHC * kHC, Wsk + (size_t)l * kHC * kHC, Wt);
        we16_kernel<<<16, 256, 0, stream>>>(We + (size_t)l * kHC * kED, We16);
        if (l == 0)
            proj_mfma_kernel<false><<<kProjBlocks, 256, 0, stream>>>(
                x, Wt,
                bq + (size_t)l * kHC, bk + (size_t)l * kHC,
                bv + (size_t)l * kHC, bsk + (size_t)l * kHC,
                (_Float16*)q16, kv8, (_Float16*)xr16);
        else
            proj_mfma_kernel<true><<<kProjBlocks, 256, 0, stream>>>(
                h16, Wt,
                bq + (size_t)l * kHC, bk + (size_t)l * kHC,
                bv + (size_t)l * kHC, bsk + (size_t)l * kHC,
                (_Float16*)q16, kv8, (_Float16*)xr16);
        qew_kernel<<<(kN + kQewNPB - 1) / kQewNPB, 256, 0, stream>>>(
            q16, We + (size_t)l * kED * kHC, qeW);
        qb_kernel<<<(kN * 4 + 255) / 256, 256, 0, stream>>>(
            q16, be + (size_t)l * kHC, qb);
        if (l == 0)
            node_kernel<false><<<kN / 2, 128, 0, stream>>>(
                (const _Float16*)q16, qeW, qb, (const _Float16*)eacs,
                kv8, rowptr, esrc,
                We16, be + (size_t)l * kHC,
                xr16, Wb + (size_t)l * 3 * kHC,
                lnw + (size_t)l * kHC, lnb + (size_t)l * kHC,
                h16);
        else
            node_kernel<true><<<kN / 2, 128, 0, stream>>>(
                (const _Float16*)q16, qeW, qb, (const _Float16*)eacs,
                kv8, rowptr, esrc,
                We16, be + (size_t)l * kHC,
                xr16, Wb + (size_t)l * 3 * kHC,
                lnw + (size_t)l * kHC, lnb + (size_t)l * kHC,
                out);
    }
}

// Round 20
// 264.400 us; speedup vs baseline: 1.1721x; 1.1721x over previous
//
#include <hip/hip_runtime.h>
#include <hip/hip_fp16.h>

constexpr int kN  = 50000;
constexpr int kE  = 400000;
constexpr int kHC = 128;
constexpr int kED = 32;
constexpr int kL  = 2;
constexpr int kScanB = (kN + 255) / 256;   // 196
constexpr int kProjBlocks = 512;           // persistent: 2 per CU
constexpr int kTiles = (kN + 31) / 32;     // 1563
constexpr int kKVB = 384;                  // bytes per kv row: 128 fp8 k + 256 fp16 v
#define EPS_LN 1e-5f
#define NEG_SLOPE 0.01f
#define RSQRT_C 0.17677669529663687f  // 1/sqrt(32)

using half8 = __attribute__((ext_vector_type(8))) _Float16;
using half4 = __attribute__((ext_vector_type(4))) _Float16;
using h2    = __attribute__((ext_vector_type(2))) _Float16;
using f32x4 = __attribute__((ext_vector_type(4))) float;

#if __has_builtin(__builtin_amdgcn_fdot2)
#define FDOT2(a, b, c) __builtin_amdgcn_fdot2((a), (b), (c), false)
#else
#define FDOT2(a, b, c) (fmaf((float)(a)[0], (float)(b)[0], \
                        fmaf((float)(a)[1], (float)(b)[1], (c))))
#endif

// ---------------- Weight transpose+convert: Wt[mat][n][k] fp16 --------------
__global__ __launch_bounds__(256) void wt_kernel(
    const float* __restrict__ Wq, const float* __restrict__ Wk,
    const float* __restrict__ Wv, const float* __restrict__ Ws,
    _Float16* __restrict__ Wt)
{
    const int g = blockIdx.x * 256 + threadIdx.x;   // 8192 total
    const int n  = g & 127;
    const int kc = (g >> 7) & 15;
    const int mat = g >> 11;
    const float* W = mat == 0 ? Wq : mat == 1 ? Wk : mat == 2 ? Wv : Ws;
    _Float16* dst = Wt + ((size_t)mat * 128 + n) * 128 + kc * 8;
#pragma unroll
    for (int i = 0; i < 8; i++) dst[i] = (_Float16)W[(kc * 8 + i) * kHC + n];
}

// ---------------- Fused weight: Wqet[o][k] = sum_{c in head(o)} Wq[k,c]We[j,c]
__global__ __launch_bounds__(256) void wqe_kernel(
    const float* __restrict__ Wq, const float* __restrict__ We,
    _Float16* __restrict__ Wqet)
{
    const int g = blockIdx.x * 256 + threadIdx.x;   // 16384
    const int o = g >> 7;          // output col (n-index for MFMA B)
    const int k = g & 127;         // input channel
    const int h = o >> 5;
    const int j = o & 31;
    const float* wq = Wq + k * kHC + h * 32;
    const float* we = We + j * kHC + h * 32;
    float s = 0.f;
#pragma unroll
    for (int i = 0; i < 32; i++) s = fmaf(wq[i], we[i], s);
    Wqet[o * 128 + k] = (_Float16)s;
}

// bqe[o] = sum_{c in head(o)} bq[c]*We[j,c]
__global__ __launch_bounds__(128) void bqe_kernel(
    const float* __restrict__ bq, const float* __restrict__ We,
    float* __restrict__ bqe)
{
    const int o = threadIdx.x;
    const int h = o >> 5;
    const int j = o & 31;
    const float* b = bq + h * 32;
    const float* we = We + j * kHC + h * 32;
    float s = 0.f;
#pragma unroll
    for (int i = 0; i < 32; i++) s = fmaf(b[i], we[i], s);
    bqe[o] = s;
}

// ---------------- We -> fp16 copy (once per layer) --------------------------
__global__ __launch_bounds__(256) void we16_kernel(
    const float* __restrict__ We, _Float16* __restrict__ We16)
{
    const int g = blockIdx.x * 256 + threadIdx.x;   // 4096
    if (g < kED * kHC) We16[g] = (_Float16)We[g];
}

// ---------------- Persistent MFMA projection (5 outputs) --------------------
// q16 [n][128], kv8 [n][384B] (k fp8 | v fp16), xr16 [n][128], qeW16 [n][128]
template<bool FP16IN>
__global__ __launch_bounds__(256, 2) void proj_mfma_kernel(
    const void* __restrict__ hin_, const _Float16* __restrict__ Wt,
    const _Float16* __restrict__ Wqet,
    const float* __restrict__ bq, const float* __restrict__ bk,
    const float* __restrict__ bv, const float* __restrict__ bs,
    const float* __restrict__ bqe,
    _Float16* __restrict__ q16, unsigned char* __restrict__ kv8,
    _Float16* __restrict__ xr16, _Float16* __restrict__ qeW16)
{
    __shared__ _Float16 lds_a[4096];          // [mt][ks][lane][8] frag-linear
    __shared__ _Float16 lds_o[5][32 * 132];   // repack staging, stride 132
    const int t = threadIdx.x;
    const int w = t >> 6;        // wave id = matrix id (0:q 1:k 2:v 3:skip)
    const int lane = t & 63;
    const int nrow = lane & 15;
    const int kc4  = (lane >> 4) * 4;

    half8 bf[32];
    {
        const _Float16* wtm = Wt + (size_t)w * 128 * 128;
#pragma unroll
        for (int ks = 0; ks < 4; ks++)
#pragma unroll
            for (int nt = 0; nt < 8; nt++)
                bf[ks * 8 + nt] = *(const half8*)
                    &wtm[(size_t)(nt * 16 + nrow) * 128 + ks * 32 + (lane >> 4) * 8];
    }

    const int sr  = t >> 3;
    const int sk0 = (t & 7) * 16;
    const int smt = sr >> 4;
    const int sl15 = sr & 15;

    float4 f[4];
    half8 hh[2];

    auto stage_to_regs = [&](int tile) {
        const int row = tile * 32 + sr;
        if (row < kN) {
            if constexpr (FP16IN) {
                const _Float16* src = (const _Float16*)hin_ + (size_t)row * kHC + sk0;
                hh[0] = *(const half8*)&src[0];
                hh[1] = *(const half8*)&src[8];
            } else {
                const float4* src = (const float4*)((const float*)hin_ + (size_t)row * kHC + sk0);
                f[0] = src[0]; f[1] = src[1]; f[2] = src[2]; f[3] = src[3];
            }
        } else {
            if constexpr (FP16IN) {
                hh[0] = half8{0, 0, 0, 0, 0, 0, 0, 0};
                hh[1] = half8{0, 0, 0, 0, 0, 0, 0, 0};
            } else {
                f[0] = f[1] = f[2] = f[3] = make_float4(0.f, 0.f, 0.f, 0.f);
            }
        }
    };

    auto regs_to_lds = [&]() {
        half8 h0, h1;
        if constexpr (FP16IN) {
            h0 = hh[0]; h1 = hh[1];
        } else {
            h0[0] = (_Float16)f[0].x; h0[1] = (_Float16)f[0].y;
            h0[2] = (_Float16)f[0].z; h0[3] = (_Float16)f[0].w;
            h0[4] = (_Float16)f[1].x; h0[5] = (_Float16)f[1].y;
            h0[6] = (_Float16)f[1].z; h0[7] = (_Float16)f[1].w;
            h1[0] = (_Float16)f[2].x; h1[1] = (_Float16)f[2].y;
            h1[2] = (_Float16)f[2].z; h1[3] = (_Float16)f[2].w;
            h1[4] = (_Float16)f[3].x; h1[5] = (_Float16)f[3].y;
            h1[6] = (_Float16)f[3].z; h1[7] = (_Float16)f[3].w;
        }
#pragma unroll
        for (int g = 0; g < 2; g++) {
            const int k  = sk0 + g * 8;
            const int ks = k >> 5;
            const int kc = (k >> 3) & 3;
            *(half8*)&lds_a[(((smt * 4 + ks) * 64) + kc * 16 + sl15) * 8] = g ? h1 : h0;
        }
    };

    const float* biasp = (w == 0) ? bq : (w == 1) ? bk : (w == 2) ? bv : bs;
    float bb[8];
#pragma unroll
    for (int nt = 0; nt < 8; nt++) bb[nt] = biasp[nt * 16 + nrow];
    float bb5[2];
#pragma unroll
    for (int u = 0; u < 2; u++) bb5[u] = bqe[(2 * w + u) * 16 + nrow];

    int tile = blockIdx.x;
    stage_to_regs(tile);

    for (;;) {
        __syncthreads();
        regs_to_lds();
        __syncthreads();

        const int next = tile + kProjBlocks;
        const bool more = next < kTiles;
        if (more) stage_to_regs(next);

        f32x4 acc[2][8];
        f32x4 acc5[2][2];
        const f32x4 z = {0.f, 0.f, 0.f, 0.f};
#pragma unroll
        for (int mt = 0; mt < 2; mt++) {
#pragma unroll
            for (int nt = 0; nt < 8; nt++) acc[mt][nt] = z;
            acc5[mt][0] = z; acc5[mt][1] = z;
        }

#pragma unroll
        for (int ks = 0; ks < 4; ks++) {
            const half8 a0 = *(const half8*)&lds_a[((0 * 4 + ks) * 64 + lane) * 8];
            const half8 a1 = *(const half8*)&lds_a[((1 * 4 + ks) * 64 + lane) * 8];
#pragma unroll
            for (int nt = 0; nt < 8; nt++) {
                acc[0][nt] = __builtin_amdgcn_mfma_f32_16x16x32_f16(a0, bf[ks * 8 + nt], acc[0][nt], 0, 0, 0);
                acc[1][nt] = __builtin_amdgcn_mfma_f32_16x16x32_f16(a1, bf[ks * 8 + nt], acc[1][nt], 0, 0, 0);
            }
            // qeW slice: this wave covers cols (2w..2w+1)*16; B frags from L2
#pragma unroll
            for (int u = 0; u < 2; u++) {
                const half8 b5 = *(const half8*)
                    &Wqet[(size_t)((2 * w + u) * 16 + nrow) * 128 + ks * 32 + (lane >> 4) * 8];
                acc5[0][u] = __builtin_amdgcn_mfma_f32_16x16x32_f16(a0, b5, acc5[0][u], 0, 0, 0);
                acc5[1][u] = __builtin_amdgcn_mfma_f32_16x16x32_f16(a1, b5, acc5[1][u], 0, 0, 0);
            }
        }

#pragma unroll
        for (int nt = 0; nt < 8; nt++) {
#pragma unroll
            for (int mt = 0; mt < 2; mt++)
#pragma unroll
                for (int r = 0; r < 4; r++)
                    lds_o[w][(mt * 16 + kc4 + r) * 132 + nt * 16 + nrow] =
                        (_Float16)(acc[mt][nt][r] + bb[nt]);
        }
#pragma unroll
        for (int u = 0; u < 2; u++) {
#pragma unroll
            for (int mt = 0; mt < 2; mt++)
#pragma unroll
                for (int r = 0; r < 4; r++)
                    lds_o[4][(mt * 16 + kc4 + r) * 132 + (2 * w + u) * 16 + nrow] =
                        (_Float16)(acc5[mt][u][r] + bb5[u]);
        }
        __syncthreads();

        const int grow = tile * 32 + sr;
        if (grow < kN) {
            {   // q
                const _Float16* s = &lds_o[0][sr * 132 + sk0];
                _Float16* d = q16 + (size_t)grow * kHC + sk0;
#pragma unroll
                for (int i = 0; i < 4; i++)
                    *(half4*)&d[i * 4] = *(const half4*)&s[i * 4];
            }
            {   // k fp8: row bytes [0,128), channel i at byte i
                const _Float16* sk = &lds_o[1][sr * 132 + sk0];
                unsigned int w4[4];
#pragma unroll
                for (int p = 0; p < 4; p++) {
                    unsigned int wd = 0;
                    wd = __builtin_amdgcn_cvt_pk_fp8_f32(
                        (float)sk[4 * p], (float)sk[4 * p + 1], wd, false);
                    wd = __builtin_amdgcn_cvt_pk_fp8_f32(
                        (float)sk[4 * p + 2], (float)sk[4 * p + 3], wd, true);
                    w4[p] = wd;
                }
                *(uint4*)(kv8 + (size_t)grow * kKVB + sk0) =
                    make_uint4(w4[0], w4[1], w4[2], w4[3]);
            }
            {   // v fp16: row bytes [128,384)
                const _Float16* sv = &lds_o[2][sr * 132 + sk0];
                _Float16* d = (_Float16*)(kv8 + (size_t)grow * kKVB + 128) + sk0;
                *(half8*)&d[0] = *(const half8*)&sv[0];
                *(half8*)&d[8] = *(const half8*)&sv[8];
            }
            {   // xr
                const _Float16* s = &lds_o[3][sr * 132 + sk0];
                _Float16* d = xr16 + (size_t)grow * kHC + sk0;
#pragma unroll
                for (int i = 0; i < 4; i++)
                    *(half4*)&d[i * 4] = *(const half4*)&s[i * 4];
            }
            {   // qeW
                const _Float16* s = &lds_o[4][sr * 132 + sk0];
                _Float16* d = qeW16 + (size_t)grow * kHC + sk0;
#pragma unroll
                for (int i = 0; i < 4; i++)
                    *(half4*)&d[i * 4] = *(const half4*)&s[i * 4];
            }
        }

        if (!more) break;
        tile = next;
    }
}

// ---------------- CSR build (once per call) ---------------------------------
__global__ __launch_bounds__(256) void hist_kernel(
    const int* __restrict__ dstI, int* __restrict__ deg)
{
    const int e = blockIdx.x * 256 + threadIdx.x;
    if (e < kE) atomicAdd(&deg[dstI[e]], 1);
}

__global__ __launch_bounds__(256) void scanA_kernel(
    const int* __restrict__ deg, int* __restrict__ locInc, int* __restrict__ blockSum)
{
    __shared__ int sm[256];
    const int t = threadIdx.x;
    const int i = blockIdx.x * 256 + t;
    sm[t] = (i < kN) ? deg[i] : 0;
    __syncthreads();
    for (int off = 1; off < 256; off <<= 1) {
        const int x = (t >= off) ? sm[t - off] : 0;
        __syncthreads();
        sm[t] += x;
        __syncthreads();
    }
    if (i < kN) locInc[i] = sm[t];
    if (t == 255) blockSum[blockIdx.x] = sm[255];
}

__global__ __launch_bounds__(256) void scanC_kernel(
    const int* __restrict__ deg, const int* __restrict__ locInc,
    const int* __restrict__ blockSum,
    int* __restrict__ rowptr, int* __restrict__ cursor)
{
    __shared__ int sm[256];
    const int t = threadIdx.x;
    const int b = blockIdx.x;
    sm[t] = (t < b) ? blockSum[t] : 0;   // b <= 195 < 256
    __syncthreads();
    for (int s = 128; s > 0; s >>= 1) {
        if (t < s) sm[t] += sm[t + s];
        __syncthreads();
    }
    const int off = sm[0];
    const int i = b * 256 + t;
    if (i < kN) {
        const int inc = locInc[i];
        const int excl = off + inc - deg[i];
        rowptr[i] = excl;
        cursor[i] = excl;
        if (i == kN - 1) rowptr[kN] = off + inc;
    }
}

__global__ __launch_bounds__(256) void scatter_kernel(
    const int* __restrict__ srcI, const int* __restrict__ dstI,
    int* __restrict__ cursor, int* __restrict__ esrc, int* __restrict__ eidx)
{
    const int e = blockIdx.x * 256 + threadIdx.x;
    if (e >= kE) return;
    const int d = dstI[e];
    const int pos = atomicAdd(&cursor[d], 1);
    esrc[pos] = srcI[e];
    eidx[pos] = e;
}

// ---------------- ea -> CSR-order fp16 copy (once per call) -----------------
__global__ __launch_bounds__(256) void ea_csr_kernel(
    const float* __restrict__ ea, const int* __restrict__ eidx,
    __half* __restrict__ eacsr)
{
    const int g = blockIdx.x * 256 + threadIdx.x;   // kE*16 threads
    if (g >= kE * 16) return;
    const int jj = g >> 4;
    const int li = g & 15;
    const int eid = eidx[jj];
    const float2 ea2 = *(const float2*)&ea[(size_t)eid * kED + 2 * li];
    *(__half2*)&eacsr[(size_t)jj * kED + 2 * li] = __floats2half2_rn(ea2.x, ea2.y);
}

// ---------------- Fused node pass: 2 edges/wave, 4 channels/lane ------------
#define PROCESS_PAIRS(U, PRED)                                               \
    {                                                                        \
        int idxv[U]; int sv[U];                                              \
        _Pragma("unroll")                                                    \
        for (int u = 0; u < U; u++) {                                        \
            idxv[u] = jj + 2 * u + half;                                     \
            if (PRED && idxv[u] >= endp) idxv[u] = beg;                      \
            sv[u] = esrc[idxv[u]];                                           \
        }                                                                    \
        unsigned int kw[U]; h2 v0[U], v1[U], e0[U], e1[U];                   \
        _Pragma("unroll")                                                    \
        for (int u = 0; u < U; u++) {                                        \
            const unsigned char* row = kv8 + (size_t)sv[u] * kKVB;           \
            kw[u] = *(const unsigned int*)(row + c4);                        \
            const _Float16* vp = (const _Float16*)(row + 128) + c4;          \
            v0[u] = *(const h2*)vp;  v1[u] = *(const h2*)(vp + 2);           \
            const _Float16* ep = eacsr + (size_t)idxv[u] * kED + lg4;        \
            e0[u] = *(const h2*)ep;  e1[u] = *(const h2*)(ep + 2);           \
        }                                                                    \
        float p[U];                                                          \
        _Pragma("unroll")                                                    \
        for (int u = 0; u < U; u++) {                                        \
            p[u] = qf[0] * __builtin_amdgcn_cvt_f32_fp8(kw[u], 0)            \
                 + qf[1] * __builtin_amdgcn_cvt_f32_fp8(kw[u], 1)            \
                 + qf[2] * __builtin_amdgcn_cvt_f32_fp8(kw[u], 2)            \
                 + qf[3] * __builtin_amdgcn_cvt_f32_fp8(kw[u], 3);           \
            p[u] = FDOT2(qwh0, e0[u], p[u]);                                 \
            p[u] = FDOT2(qwh1, e1[u], p[u]);                                 \
        }                                                                    \
        _Pragma("unroll")                                                    \
        for (int m = 1; m <= 4; m <<= 1) {                                   \
            _Pragma("unroll")                                                \
            for (int u = 0; u < U; u++) p[u] += __shfl_xor(p[u], m);         \
        }                                                                    \
        _Pragma("unroll")                                                    \
        for (int u = 0; u < U; u++) {                                        \
            float a = __expf((p[u] + qbv) * RSQRT_C);                        \
            if (PRED && (jj + 2 * u + half >= endp)) a = 0.f;                \
            den += a;                                                        \
            acc[0] = fmaf((float)v0[u][0], a, acc[0]);                       \
            acc[1] = fmaf((float)v0[u][1], a, acc[1]);                       \
            acc[2] = fmaf((float)v1[u][0], a, acc[2]);                       \
            acc[3] = fmaf((float)v1[u][1], a, acc[3]);                       \
            t4[0] = fmaf((float)e0[u][0], a, t4[0]);                         \
            t4[1] = fmaf((float)e0[u][1], a, t4[1]);                         \
            t4[2] = fmaf((float)e1[u][0], a, t4[2]);                         \
            t4[3] = fmaf((float)e1[u][1], a, t4[3]);                         \
        }                                                                    \
    }

template<bool LAST>
__global__ __launch_bounds__(128) void node_kernel(
    const _Float16* __restrict__ q16, const __half* __restrict__ qeW,
    const _Float16* __restrict__ eacsr,
    const unsigned char* __restrict__ kv8,
    const int* __restrict__ rowptr, const int* __restrict__ esrc,
    const _Float16* __restrict__ We16, const float* __restrict__ be,
    const __half* __restrict__ xr16, const float* __restrict__ Wb,
    const float* __restrict__ lnw, const float* __restrict__ lnb,
    void* __restrict__ hout)
{
    __shared__ __half wes[kED * kHC];   // 8 KB
    const int t = threadIdx.x;
    {
        float4* d4 = (float4*)wes;
        const float4* s4 = (const float4*)We16;
#pragma unroll
        for (int i = 0; i < 4; i++) d4[t + 128 * i] = s4[t + 128 * i];
    }
    __syncthreads();

    const int n = blockIdx.x * 2 + (t >> 6);   // kN % 2 == 0
    const int lane = t & 63;
    const int hl   = lane & 31;
    const int half = lane >> 5;
    const int hd   = hl >> 3;
    const int lg   = hl & 7;
    const int c4   = hd * 32 + lg * 4;
    const int lg4  = lg * 4;

    float qf[4];
    h2 qwh0, qwh1;
    {
        const h2 qa = *(const h2*)&q16[n * kHC + c4];
        const h2 qbx = *(const h2*)&q16[n * kHC + c4 + 2];
        qf[0] = (float)qa[0];  qf[1] = (float)qa[1];
        qf[2] = (float)qbx[0]; qf[3] = (float)qbx[1];
        const _Float16* qw = (const _Float16*)qeW + n * kHC + c4;
        qwh0 = *(const h2*)qw;
        qwh1 = *(const h2*)(qw + 2);
    }
    // qb inline: sum_{c in head} q[c]*be[c] via 8-lane reduce
    float qbv;
    {
        const float4 bev = *(const float4*)&be[c4];
        qbv = qf[0] * bev.x + qf[1] * bev.y + qf[2] * bev.z + qf[3] * bev.w;
#pragma unroll
        for (int m = 1; m <= 4; m <<= 1) qbv += __shfl_xor(qbv, m);
    }

    float acc[4] = {0.f, 0.f, 0.f, 0.f};
    float t4[4]  = {0.f, 0.f, 0.f, 0.f};
    float den = 0.f;
    const int beg = rowptr[n], endp = rowptr[n + 1];

    int jj = beg;
    for (; jj + 8 <= endp; jj += 8) PROCESS_PAIRS(4, 0)
    for (; jj + 4 <= endp; jj += 4) PROCESS_PAIRS(2, 0)
    for (; jj < endp; jj += 2)      PROCESS_PAIRS(1, 1)

    den += __shfl_xor(den, 32);
#pragma unroll
    for (int i = 0; i < 4; i++) {
        acc[i] += __shfl_xor(acc[i], 32);
        t4[i]  += __shfl_xor(t4[i], 32);
    }

    const float invd = 1.f / (den + 1e-16f);
    float o[4], tn[4];
#pragma unroll
    for (int i = 0; i < 4; i++) { o[i] = acc[i] * invd; tn[i] = t4[i] * invd; }

    const int gb = (lane & 32) | (hd * 8);
#pragma unroll
    for (int jo = 0; jo < 8; jo++) {
        float Tv[4];
#pragma unroll
        for (int ji = 0; ji < 4; ji++) Tv[ji] = __shfl(tn[ji], gb | jo);
#pragma unroll
        for (int ji = 0; ji < 4; ji++) {
            const int j = jo * 4 + ji;
            const float2 wA = __half22float2(*(const __half2*)&wes[j * kHC + c4]);
            const float2 wB = __half22float2(*(const __half2*)&wes[j * kHC + c4 + 2]);
            o[0] = fmaf(Tv[ji], wA.x, o[0]);
            o[1] = fmaf(Tv[ji], wA.y, o[1]);
            o[2] = fmaf(Tv[ji], wB.x, o[2]);
            o[3] = fmaf(Tv[ji], wB.y, o[3]);
        }
    }
#pragma unroll
    for (int i = 0; i < 4; i++) o[i] += be[c4 + i];

    float r[4];
    {
        const float2 rA = __half22float2(*(const __half2*)&xr16[(size_t)n * kHC + c4]);
        const float2 rB = __half22float2(*(const __half2*)&xr16[(size_t)n * kHC + c4 + 2]);
        r[0] = rA.x; r[1] = rA.y; r[2] = rB.x; r[3] = rB.y;
    }
    float z = 0.f;
#pragma unroll
    for (int i = 0; i < 4; i++) {
        z += o[i] * Wb[c4 + i] + r[i] * Wb[kHC + c4 + i]
           + (o[i] - r[i]) * Wb[2 * kHC + c4 + i];
    }
#pragma unroll
    for (int m = 1; m < 32; m <<= 1) z += __shfl_xor(z, m);
    const float beta = 1.f / (1.f + __expf(-z));

    float gv[4];
    float sm = 0.f, sq = 0.f;
#pragma unroll
    for (int i = 0; i < 4; i++) {
        gv[i] = beta * r[i] + (1.f - beta) * o[i];
        sm += gv[i];
        sq += gv[i] * gv[i];
    }
#pragma unroll
    for (int m = 1; m < 32; m <<= 1) {
        sm += __shfl_xor(sm, m);
        sq += __shfl_xor(sq, m);
    }
    const float mu  = sm * (1.f / kHC);
    const float var = sq * (1.f / kHC) - mu * mu;
    const float inv = rsqrtf(var + EPS_LN);

    float y[4];
#pragma unroll
    for (int i = 0; i < 4; i++) {
        float yy = (gv[i] - mu) * inv * lnw[c4 + i] + lnb[c4 + i];
        y[i] = yy > 0.f ? yy : NEG_SLOPE * yy;
    }
    if (half == 0) {
        if constexpr (LAST) {
            *(float4*)&((float*)hout)[(size_t)n * kHC + c4] =
                make_float4(y[0], y[1], y[2], y[3]);
        } else {
            half4 hv;
            hv[0] = (_Float16)y[0]; hv[1] = (_Float16)y[1];
            hv[2] = (_Float16)y[2]; hv[3] = (_Float16)y[3];
            *(half4*)&((__half*)hout)[(size_t)n * kHC + c4] = hv;
        }
    }
}

extern "C" void kernel_launch(void* const* d_in, const int* in_sizes, int n_in,
                              void* d_out, int out_size, void* d_ws, size_t ws_size,
                              hipStream_t stream)
{
    const float* x   = (const float*)d_in[0];
    const int*   ei  = (const int*)d_in[1];
    const float* ea  = (const float*)d_in[2];
    const float* Wq  = (const float*)d_in[3];
    const float* bq  = (const float*)d_in[4];
    const float* Wk  = (const float*)d_in[5];
    const float* bk  = (const float*)d_in[6];
    const float* Wv  = (const float*)d_in[7];
    const float* bv  = (const float*)d_in[8];
    const float* We  = (const float*)d_in[9];
    const float* be  = (const float*)d_in[10];
    const float* Wsk = (const float*)d_in[11];
    const float* bsk = (const float*)d_in[12];
    const float* Wb  = (const float*)d_in[13];
    const float* lnw = (const float*)d_in[14];
    const float* lnb = (const float*)d_in[15];
    float* out = (float*)d_out;

    const int* srcI = ei;
    const int* dstI = ei + kE;

    // ---- workspace layout (~95 MB) ----
    __half* q16  = (__half*)d_ws;
    unsigned char* kv8 = (unsigned char*)(q16 + (size_t)kN * kHC);  // [n][384B]
    __half* qeW  = (__half*)(kv8 + (size_t)kN * kKVB);
    __half* xr16 = qeW + (size_t)kN * kHC;
    __half* h16  = xr16 + (size_t)kN * kHC;
    int* deg     = (int*)(h16 + (size_t)kN * kHC);
    int* rowptr  = deg + kN;
    int* cursor  = rowptr + kN + 1;
    int* esrc    = cursor + kN;
    int* eidx    = esrc + kE;
    __half* eacs = (__half*)(eidx + kE);
    _Float16* Wt = (_Float16*)(eacs + (size_t)kE * kED);   // 128 KB
    _Float16* We16 = Wt + 4 * 128 * 128;                   // 8 KB
    _Float16* Wqet = We16 + kED * kHC;                     // 32 KB
    float* bqe   = (float*)(Wqet + 128 * 128);             // 512 B
    int* locInc  = (int*)(bqe + 128);
    int* blockSum = locInc + kN;

    // ---- CSR build (edge_index constant across layers) ----
    hipMemsetAsync(deg, 0, (size_t)kN * sizeof(int), stream);
    hist_kernel<<<(kE + 255) / 256, 256, 0, stream>>>(dstI, deg);
    scanA_kernel<<<kScanB, 256, 0, stream>>>(deg, locInc, blockSum);
    scanC_kernel<<<kScanB, 256, 0, stream>>>(deg, locInc, blockSum, rowptr, cursor);
    scatter_kernel<<<(kE + 255) / 256, 256, 0, stream>>>(srcI, dstI, cursor, esrc, eidx);
    ea_csr_kernel<<<(kE * 16 + 255) / 256, 256, 0, stream>>>(ea, eidx, eacs);

    for (int l = 0; l < kL; l++) {
        wt_kernel<<<32, 256, 0, stream>>>(
            Wq + (size_t)l * kHC * kHC, Wk + (size_t)l * kHC * kHC,
            Wv + (size_t)l * kHC * kHC, Wsk + (size_t)l * kHC * kHC, Wt);
        we16_kernel<<<16, 256, 0, stream>>>(We + (size_t)l * kHC * kED, We16);
        wqe_kernel<<<64, 256, 0, stream>>>(
            Wq + (size_t)l * kHC * kHC, We + (size_t)l * kED * kHC, Wqet);
        bqe_kernel<<<1, 128, 0, stream>>>(
            bq + (size_t)l * kHC, We + (size_t)l * kED * kHC, bqe);
        if (l == 0)
            proj_mfma_kernel<false><<<kProjBlocks, 256, 0, stream>>>(
                x, Wt, Wqet,
                bq + (size_t)l * kHC, bk + (size_t)l * kHC,
                bv + (size_t)l * kHC, bsk + (size_t)l * kHC, bqe,
                (_Float16*)q16, kv8, (_Float16*)xr16, (_Float16*)qeW);
        else
            proj_mfma_kernel<true><<<kProjBlocks, 256, 0, stream>>>(
                h16, Wt, Wqet,
                bq + (size_t)l * kHC, bk + (size_t)l * kHC,
                bv + (size_t)l * kHC, bsk + (size_t)l * kHC, bqe,
                (_Float16*)q16, kv8, (_Float16*)xr16, (_Float16*)qeW);
        if (l == 0)
            node_kernel<false><<<kN / 2, 128, 0, stream>>>(
                (const _Float16*)q16, qeW, (const _Float16*)eacs,
                kv8, rowptr, esrc,
                We16, be + (size_t)l * kHC,
                xr16, Wb + (size_t)l * 3 * kHC,
                lnw + (size_t)l * kHC, lnb + (size_t)l * kHC,
                h16);
        else
            node_kernel<true><<<kN / 2, 128, 0, stream>>>(
                (const _Float16*)q16, qeW, (const _Float16*)eacs,
                kv8, rowptr, esrc,
                We16, be + (size_t)l * kHC,
                xr16, Wb + (size_t)l * 3 * kHC,
                lnw + (size_t)l * kHC, lnb + (size_t)l * kHC,
                out);
    }
}

// Round 21
// 253.225 us; speedup vs baseline: 1.2239x; 1.0441x over previous
//
#include <hip/hip_runtime.h>
#include <hip/hip_fp16.h>

constexpr int kN  = 50000;
constexpr int kE  = 400000;
constexpr int kHC = 128;
constexpr int kED = 32;
constexpr int kL  = 2;
constexpr int kScanB = (kN + 255) / 256;   // 196
constexpr int kProjBlocks = 512;           // persistent: 2 per CU
constexpr int kTiles = (kN + 31) / 32;     // 1563
constexpr int kKVB = 384;                  // bytes per kv row: 128 fp8 k + 256 fp16 v
#define EPS_LN 1e-5f
#define NEG_SLOPE 0.01f
#define RSQRT_C 0.17677669529663687f  // 1/sqrt(32)

using half8 = __attribute__((ext_vector_type(8))) _Float16;
using half4 = __attribute__((ext_vector_type(4))) _Float16;
using h2    = __attribute__((ext_vector_type(2))) _Float16;
using f32x4 = __attribute__((ext_vector_type(4))) float;

#if __has_builtin(__builtin_amdgcn_fdot2)
#define FDOT2(a, b, c) __builtin_amdgcn_fdot2((a), (b), (c), false)
#else
#define FDOT2(a, b, c) (fmaf((float)(a)[0], (float)(b)[0], \
                        fmaf((float)(a)[1], (float)(b)[1], (c))))
#endif

// ---------------- Fused per-layer prep: Wt | We16 | Wqet | bqe --------------
// blocks [0,32): Wt transpose+cvt; [32,48): We16 cvt; [48,112): Wqet fused
// weight; block 112: bqe.
__global__ __launch_bounds__(256) void prep_kernel(
    const float* __restrict__ Wq, const float* __restrict__ Wk,
    const float* __restrict__ Wv, const float* __restrict__ Ws,
    const float* __restrict__ We, const float* __restrict__ bq,
    _Float16* __restrict__ Wt, _Float16* __restrict__ We16,
    _Float16* __restrict__ Wqet, float* __restrict__ bqe)
{
    const int b = blockIdx.x;
    const int t = threadIdx.x;
    if (b < 32) {
        const int g = b * 256 + t;          // 8192
        const int n  = g & 127;
        const int kc = (g >> 7) & 15;
        const int mat = g >> 11;
        const float* W = mat == 0 ? Wq : mat == 1 ? Wk : mat == 2 ? Wv : Ws;
        _Float16* dst = Wt + ((size_t)mat * 128 + n) * 128 + kc * 8;
#pragma unroll
        for (int i = 0; i < 8; i++) dst[i] = (_Float16)W[(kc * 8 + i) * kHC + n];
    } else if (b < 48) {
        const int g = (b - 32) * 256 + t;   // 4096
        We16[g] = (_Float16)We[g];
    } else if (b < 112) {
        const int g = (b - 48) * 256 + t;   // 16384
        const int o = g >> 7;               // output col
        const int k = g & 127;              // input channel
        const int h = o >> 5;
        const int j = o & 31;
        const float* wq = Wq + k * kHC + h * 32;
        const float* we = We + j * kHC + h * 32;
        float s = 0.f;
#pragma unroll
        for (int i = 0; i < 32; i++) s = fmaf(wq[i], we[i], s);
        Wqet[o * 128 + k] = (_Float16)s;
    } else {
        if (t < 128) {
            const int o = t;
            const int h = o >> 5;
            const int j = o & 31;
            const float* bb = bq + h * 32;
            const float* we = We + j * kHC + h * 32;
            float s = 0.f;
#pragma unroll
            for (int i = 0; i < 32; i++) s = fmaf(bb[i], we[i], s);
            bqe[o] = s;
        }
    }
}

// ---------------- Persistent MFMA projection (5 outputs) --------------------
// q16 [n][128], kv8 [n][384B] (k fp8 | v fp16), xr16 [n][128], qeW16 [n][128]
template<bool FP16IN>
__global__ __launch_bounds__(256, 2) void proj_mfma_kernel(
    const void* __restrict__ hin_, const _Float16* __restrict__ Wt,
    const _Float16* __restrict__ Wqet,
    const float* __restrict__ bq, const float* __restrict__ bk,
    const float* __restrict__ bv, const float* __restrict__ bs,
    const float* __restrict__ bqe,
    _Float16* __restrict__ q16, unsigned char* __restrict__ kv8,
    _Float16* __restrict__ xr16, _Float16* __restrict__ qeW16)
{
    __shared__ _Float16 lds_a[4096];          // [mt][ks][lane][8] frag-linear
    __shared__ _Float16 lds_o[5][32 * 132];   // repack staging, stride 132
    const int t = threadIdx.x;
    const int w = t >> 6;        // wave id = matrix id (0:q 1:k 2:v 3:skip)
    const int lane = t & 63;
    const int nrow = lane & 15;
    const int kc4  = (lane >> 4) * 4;

    half8 bf[32];
    {
        const _Float16* wtm = Wt + (size_t)w * 128 * 128;
#pragma unroll
        for (int ks = 0; ks < 4; ks++)
#pragma unroll
            for (int nt = 0; nt < 8; nt++)
                bf[ks * 8 + nt] = *(const half8*)
                    &wtm[(size_t)(nt * 16 + nrow) * 128 + ks * 32 + (lane >> 4) * 8];
    }

    const int sr  = t >> 3;
    const int sk0 = (t & 7) * 16;
    const int smt = sr >> 4;
    const int sl15 = sr & 15;

    float4 f[4];
    half8 hh[2];

    auto stage_to_regs = [&](int tile) {
        const int row = tile * 32 + sr;
        if (row < kN) {
            if constexpr (FP16IN) {
                const _Float16* src = (const _Float16*)hin_ + (size_t)row * kHC + sk0;
                hh[0] = *(const half8*)&src[0];
                hh[1] = *(const half8*)&src[8];
            } else {
                const float4* src = (const float4*)((const float*)hin_ + (size_t)row * kHC + sk0);
                f[0] = src[0]; f[1] = src[1]; f[2] = src[2]; f[3] = src[3];
            }
        } else {
            if constexpr (FP16IN) {
                hh[0] = half8{0, 0, 0, 0, 0, 0, 0, 0};
                hh[1] = half8{0, 0, 0, 0, 0, 0, 0, 0};
            } else {
                f[0] = f[1] = f[2] = f[3] = make_float4(0.f, 0.f, 0.f, 0.f);
            }
        }
    };

    auto regs_to_lds = [&]() {
        half8 h0, h1;
        if constexpr (FP16IN) {
            h0 = hh[0]; h1 = hh[1];
        } else {
            h0[0] = (_Float16)f[0].x; h0[1] = (_Float16)f[0].y;
            h0[2] = (_Float16)f[0].z; h0[3] = (_Float16)f[0].w;
            h0[4] = (_Float16)f[1].x; h0[5] = (_Float16)f[1].y;
            h0[6] = (_Float16)f[1].z; h0[7] = (_Float16)f[1].w;
            h1[0] = (_Float16)f[2].x; h1[1] = (_Float16)f[2].y;
            h1[2] = (_Float16)f[2].z; h1[3] = (_Float16)f[2].w;
            h1[4] = (_Float16)f[3].x; h1[5] = (_Float16)f[3].y;
            h1[6] = (_Float16)f[3].z; h1[7] = (_Float16)f[3].w;
        }
#pragma unroll
        for (int g = 0; g < 2; g++) {
            const int k  = sk0 + g * 8;
            const int ks = k >> 5;
            const int kc = (k >> 3) & 3;
            *(half8*)&lds_a[(((smt * 4 + ks) * 64) + kc * 16 + sl15) * 8] = g ? h1 : h0;
        }
    };

    const float* biasp = (w == 0) ? bq : (w == 1) ? bk : (w == 2) ? bv : bs;
    float bb[8];
#pragma unroll
    for (int nt = 0; nt < 8; nt++) bb[nt] = biasp[nt * 16 + nrow];
    float bb5[2];
#pragma unroll
    for (int u = 0; u < 2; u++) bb5[u] = bqe[(2 * w + u) * 16 + nrow];

    int tile = blockIdx.x;
    stage_to_regs(tile);

    for (;;) {
        __syncthreads();
        regs_to_lds();
        __syncthreads();

        const int next = tile + kProjBlocks;
        const bool more = next < kTiles;
        if (more) stage_to_regs(next);

        f32x4 acc[2][8];
        f32x4 acc5[2][2];
        const f32x4 z = {0.f, 0.f, 0.f, 0.f};
#pragma unroll
        for (int mt = 0; mt < 2; mt++) {
#pragma unroll
            for (int nt = 0; nt < 8; nt++) acc[mt][nt] = z;
            acc5[mt][0] = z; acc5[mt][1] = z;
        }

#pragma unroll
        for (int ks = 0; ks < 4; ks++) {
            const half8 a0 = *(const half8*)&lds_a[((0 * 4 + ks) * 64 + lane) * 8];
            const half8 a1 = *(const half8*)&lds_a[((1 * 4 + ks) * 64 + lane) * 8];
#pragma unroll
            for (int nt = 0; nt < 8; nt++) {
                acc[0][nt] = __builtin_amdgcn_mfma_f32_16x16x32_f16(a0, bf[ks * 8 + nt], acc[0][nt], 0, 0, 0);
                acc[1][nt] = __builtin_amdgcn_mfma_f32_16x16x32_f16(a1, bf[ks * 8 + nt], acc[1][nt], 0, 0, 0);
            }
#pragma unroll
            for (int u = 0; u < 2; u++) {
                const half8 b5 = *(const half8*)
                    &Wqet[(size_t)((2 * w + u) * 16 + nrow) * 128 + ks * 32 + (lane >> 4) * 8];
                acc5[0][u] = __builtin_amdgcn_mfma_f32_16x16x32_f16(a0, b5, acc5[0][u], 0, 0, 0);
                acc5[1][u] = __builtin_amdgcn_mfma_f32_16x16x32_f16(a1, b5, acc5[1][u], 0, 0, 0);
            }
        }

#pragma unroll
        for (int nt = 0; nt < 8; nt++) {
#pragma unroll
            for (int mt = 0; mt < 2; mt++)
#pragma unroll
                for (int r = 0; r < 4; r++)
                    lds_o[w][(mt * 16 + kc4 + r) * 132 + nt * 16 + nrow] =
                        (_Float16)(acc[mt][nt][r] + bb[nt]);
        }
#pragma unroll
        for (int u = 0; u < 2; u++) {
#pragma unroll
            for (int mt = 0; mt < 2; mt++)
#pragma unroll
                for (int r = 0; r < 4; r++)
                    lds_o[4][(mt * 16 + kc4 + r) * 132 + (2 * w + u) * 16 + nrow] =
                        (_Float16)(acc5[mt][u][r] + bb5[u]);
        }
        __syncthreads();

        const int grow = tile * 32 + sr;
        if (grow < kN) {
            {   // q
                const _Float16* s = &lds_o[0][sr * 132 + sk0];
                _Float16* d = q16 + (size_t)grow * kHC + sk0;
#pragma unroll
                for (int i = 0; i < 4; i++)
                    *(half4*)&d[i * 4] = *(const half4*)&s[i * 4];
            }
            {   // k fp8: row bytes [0,128), channel i at byte i
                const _Float16* sk = &lds_o[1][sr * 132 + sk0];
                unsigned int w4[4];
#pragma unroll
                for (int p = 0; p < 4; p++) {
                    unsigned int wd = 0;
                    wd = __builtin_amdgcn_cvt_pk_fp8_f32(
                        (float)sk[4 * p], (float)sk[4 * p + 1], wd, false);
                    wd = __builtin_amdgcn_cvt_pk_fp8_f32(
                        (float)sk[4 * p + 2], (float)sk[4 * p + 3], wd, true);
                    w4[p] = wd;
                }
                *(uint4*)(kv8 + (size_t)grow * kKVB + sk0) =
                    make_uint4(w4[0], w4[1], w4[2], w4[3]);
            }
            {   // v fp16: row bytes [128,384)
                const _Float16* sv = &lds_o[2][sr * 132 + sk0];
                _Float16* d = (_Float16*)(kv8 + (size_t)grow * kKVB + 128) + sk0;
                *(half8*)&d[0] = *(const half8*)&sv[0];
                *(half8*)&d[8] = *(const half8*)&sv[8];
            }
            {   // xr
                const _Float16* s = &lds_o[3][sr * 132 + sk0];
                _Float16* d = xr16 + (size_t)grow * kHC + sk0;
#pragma unroll
                for (int i = 0; i < 4; i++)
                    *(half4*)&d[i * 4] = *(const half4*)&s[i * 4];
            }
            {   // qeW
                const _Float16* s = &lds_o[4][sr * 132 + sk0];
                _Float16* d = qeW16 + (size_t)grow * kHC + sk0;
#pragma unroll
                for (int i = 0; i < 4; i++)
                    *(half4*)&d[i * 4] = *(const half4*)&s[i * 4];
            }
        }

        if (!more) break;
        tile = next;
    }
}

// ---------------- CSR build (once per call) ---------------------------------
__global__ __launch_bounds__(256) void hist_kernel(
    const int* __restrict__ dstI, int* __restrict__ deg)
{
    const int e = blockIdx.x * 256 + threadIdx.x;
    if (e < kE) atomicAdd(&deg[dstI[e]], 1);
}

__global__ __launch_bounds__(256) void scanA_kernel(
    const int* __restrict__ deg, int* __restrict__ locInc, int* __restrict__ blockSum)
{
    __shared__ int sm[256];
    const int t = threadIdx.x;
    const int i = blockIdx.x * 256 + t;
    sm[t] = (i < kN) ? deg[i] : 0;
    __syncthreads();
    for (int off = 1; off < 256; off <<= 1) {
        const int x = (t >= off) ? sm[t - off] : 0;
        __syncthreads();
        sm[t] += x;
        __syncthreads();
    }
    if (i < kN) locInc[i] = sm[t];
    if (t == 255) blockSum[blockIdx.x] = sm[255];
}

__global__ __launch_bounds__(256) void scanC_kernel(
    const int* __restrict__ deg, const int* __restrict__ locInc,
    const int* __restrict__ blockSum,
    int* __restrict__ rowptr, int* __restrict__ cursor)
{
    __shared__ int sm[256];
    const int t = threadIdx.x;
    const int b = blockIdx.x;
    sm[t] = (t < b) ? blockSum[t] : 0;   // b <= 195 < 256
    __syncthreads();
    for (int s = 128; s > 0; s >>= 1) {
        if (t < s) sm[t] += sm[t + s];
        __syncthreads();
    }
    const int off = sm[0];
    const int i = b * 256 + t;
    if (i < kN) {
        const int inc = locInc[i];
        const int excl = off + inc - deg[i];
        rowptr[i] = excl;
        cursor[i] = excl;
        if (i == kN - 1) rowptr[kN] = off + inc;
    }
}

__global__ __launch_bounds__(256) void scatter_kernel(
    const int* __restrict__ srcI, const int* __restrict__ dstI,
    int* __restrict__ cursor, int* __restrict__ esrc, int* __restrict__ eidx)
{
    const int e = blockIdx.x * 256 + threadIdx.x;
    if (e >= kE) return;
    const int d = dstI[e];
    const int pos = atomicAdd(&cursor[d], 1);
    esrc[pos] = srcI[e];
    eidx[pos] = e;
}

// ---------------- ea -> CSR-order fp16 copy (once per call) -----------------
__global__ __launch_bounds__(256) void ea_csr_kernel(
    const float* __restrict__ ea, const int* __restrict__ eidx,
    __half* __restrict__ eacsr)
{
    const int g = blockIdx.x * 256 + threadIdx.x;   // kE*16 threads
    if (g >= kE * 16) return;
    const int jj = g >> 4;
    const int li = g & 15;
    const int eid = eidx[jj];
    const float2 ea2 = *(const float2*)&ea[(size_t)eid * kED + 2 * li];
    *(__half2*)&eacsr[(size_t)jj * kED + 2 * li] = __floats2half2_rn(ea2.x, ea2.y);
}

// ---------------- Fused node pass: 2 edges/wave, 4 channels/lane ------------
#define PROCESS_PAIRS(U, PRED)                                               \
    {                                                                        \
        int idxv[U]; int sv[U];                                              \
        _Pragma("unroll")                                                    \
        for (int u = 0; u < U; u++) {                                        \
            idxv[u] = jj + 2 * u + half;                                     \
            if (PRED && idxv[u] >= endp) idxv[u] = beg;                      \
            sv[u] = esrc[idxv[u]];                                           \
        }                                                                    \
        unsigned int kw[U]; h2 v0[U], v1[U], e0[U], e1[U];                   \
        _Pragma("unroll")                                                    \
        for (int u = 0; u < U; u++) {                                        \
            const unsigned char* row = kv8 + (size_t)sv[u] * kKVB;           \
            kw[u] = *(const unsigned int*)(row + c4);                        \
            const _Float16* vp = (const _Float16*)(row + 128) + c4;          \
            v0[u] = *(const h2*)vp;  v1[u] = *(const h2*)(vp + 2);           \
            const _Float16* ep = eacsr + (size_t)idxv[u] * kED + lg4;        \
            e0[u] = *(const h2*)ep;  e1[u] = *(const h2*)(ep + 2);           \
        }                                                                    \
        float p[U];                                                          \
        _Pragma("unroll")                                                    \
        for (int u = 0; u < U; u++) {                                        \
            p[u] = qf[0] * __builtin_amdgcn_cvt_f32_fp8(kw[u], 0)            \
                 + qf[1] * __builtin_amdgcn_cvt_f32_fp8(kw[u], 1)            \
                 + qf[2] * __builtin_amdgcn_cvt_f32_fp8(kw[u], 2)            \
                 + qf[3] * __builtin_amdgcn_cvt_f32_fp8(kw[u], 3);           \
            p[u] = FDOT2(qwh0, e0[u], p[u]);                                 \
            p[u] = FDOT2(qwh1, e1[u], p[u]);                                 \
        }                                                                    \
        _Pragma("unroll")                                                    \
        for (int m = 1; m <= 4; m <<= 1) {                                   \
            _Pragma("unroll")                                                \
            for (int u = 0; u < U; u++) p[u] += __shfl_xor(p[u], m);         \
        }                                                                    \
        _Pragma("unroll")                                                    \
        for (int u = 0; u < U; u++) {                                        \
            float a = __expf((p[u] + qbv) * RSQRT_C);                        \
            if (PRED && (jj + 2 * u + half >= endp)) a = 0.f;                \
            den += a;                                                        \
            acc[0] = fmaf((float)v0[u][0], a, acc[0]);                       \
            acc[1] = fmaf((float)v0[u][1], a, acc[1]);                       \
            acc[2] = fmaf((float)v1[u][0], a, acc[2]);                       \
            acc[3] = fmaf((float)v1[u][1], a, acc[3]);                       \
            t4[0] = fmaf((float)e0[u][0], a, t4[0]);                         \
            t4[1] = fmaf((float)e0[u][1], a, t4[1]);                         \
            t4[2] = fmaf((float)e1[u][0], a, t4[2]);                         \
            t4[3] = fmaf((float)e1[u][1], a, t4[3]);                         \
        }                                                                    \
    }

template<bool LAST>
__global__ __launch_bounds__(128) void node_kernel(
    const _Float16* __restrict__ q16, const __half* __restrict__ qeW,
    const _Float16* __restrict__ eacsr,
    const unsigned char* __restrict__ kv8,
    const int* __restrict__ rowptr, const int* __restrict__ esrc,
    const _Float16* __restrict__ We16, const float* __restrict__ be,
    const __half* __restrict__ xr16, const float* __restrict__ Wb,
    const float* __restrict__ lnw, const float* __restrict__ lnb,
    void* __restrict__ hout)
{
    __shared__ __half wes[kED * kHC];   // 8 KB
    const int t = threadIdx.x;
    {
        float4* d4 = (float4*)wes;
        const float4* s4 = (const float4*)We16;
#pragma unroll
        for (int i = 0; i < 4; i++) d4[t + 128 * i] = s4[t + 128 * i];
    }
    __syncthreads();

    const int n = blockIdx.x * 2 + (t >> 6);   // kN % 2 == 0
    const int lane = t & 63;
    const int hl   = lane & 31;
    const int half = lane >> 5;
    const int hd   = hl >> 3;
    const int lg   = hl & 7;
    const int c4   = hd * 32 + lg * 4;
    const int lg4  = lg * 4;

    float qf[4];
    h2 qwh0, qwh1;
    {
        const h2 qa = *(const h2*)&q16[n * kHC + c4];
        const h2 qbx = *(const h2*)&q16[n * kHC + c4 + 2];
        qf[0] = (float)qa[0];  qf[1] = (float)qa[1];
        qf[2] = (float)qbx[0]; qf[3] = (float)qbx[1];
        const _Float16* qw = (const _Float16*)qeW + n * kHC + c4;
        qwh0 = *(const h2*)qw;
        qwh1 = *(const h2*)(qw + 2);
    }
    float qbv;
    {
        const float4 bev = *(const float4*)&be[c4];
        qbv = qf[0] * bev.x + qf[1] * bev.y + qf[2] * bev.z + qf[3] * bev.w;
#pragma unroll
        for (int m = 1; m <= 4; m <<= 1) qbv += __shfl_xor(qbv, m);
    }

    float acc[4] = {0.f, 0.f, 0.f, 0.f};
    float t4[4]  = {0.f, 0.f, 0.f, 0.f};
    float den = 0.f;
    const int beg = rowptr[n], endp = rowptr[n + 1];

    int jj = beg;
    for (; jj + 8 <= endp; jj += 8) PROCESS_PAIRS(4, 0)
    for (; jj + 4 <= endp; jj += 4) PROCESS_PAIRS(2, 0)
    for (; jj < endp; jj += 2)      PROCESS_PAIRS(1, 1)

    den += __shfl_xor(den, 32);
#pragma unroll
    for (int i = 0; i < 4; i++) {
        acc[i] += __shfl_xor(acc[i], 32);
        t4[i]  += __shfl_xor(t4[i], 32);
    }

    const float invd = 1.f / (den + 1e-16f);
    float o[4], tn[4];
#pragma unroll
    for (int i = 0; i < 4; i++) { o[i] = acc[i] * invd; tn[i] = t4[i] * invd; }

    const int gb = (lane & 32) | (hd * 8);
#pragma unroll
    for (int jo = 0; jo < 8; jo++) {
        float Tv[4];
#pragma unroll
        for (int ji = 0; ji < 4; ji++) Tv[ji] = __shfl(tn[ji], gb | jo);
#pragma unroll
        for (int ji = 0; ji < 4; ji++) {
            const int j = jo * 4 + ji;
            const float2 wA = __half22float2(*(const __half2*)&wes[j * kHC + c4]);
            const float2 wB = __half22float2(*(const __half2*)&wes[j * kHC + c4 + 2]);
            o[0] = fmaf(Tv[ji], wA.x, o[0]);
            o[1] = fmaf(Tv[ji], wA.y, o[1]);
            o[2] = fmaf(Tv[ji], wB.x, o[2]);
            o[3] = fmaf(Tv[ji], wB.y, o[3]);
        }
    }
#pragma unroll
    for (int i = 0; i < 4; i++) o[i] += be[c4 + i];

    float r[4];
    {
        const float2 rA = __half22float2(*(const __half2*)&xr16[(size_t)n * kHC + c4]);
        const float2 rB = __half22float2(*(const __half2*)&xr16[(size_t)n * kHC + c4 + 2]);
        r[0] = rA.x; r[1] = rA.y; r[2] = rB.x; r[3] = rB.y;
    }
    float z = 0.f;
#pragma unroll
    for (int i = 0; i < 4; i++) {
        z += o[i] * Wb[c4 + i] + r[i] * Wb[kHC + c4 + i]
           + (o[i] - r[i]) * Wb[2 * kHC + c4 + i];
    }
#pragma unroll
    for (int m = 1; m < 32; m <<= 1) z += __shfl_xor(z, m);
    const float beta = 1.f / (1.f + __expf(-z));

    float gv[4];
    float sm = 0.f, sq = 0.f;
#pragma unroll
    for (int i = 0; i < 4; i++) {
        gv[i] = beta * r[i] + (1.f - beta) * o[i];
        sm += gv[i];
        sq += gv[i] * gv[i];
    }
#pragma unroll
    for (int m = 1; m < 32; m <<= 1) {
        sm += __shfl_xor(sm, m);
        sq += __shfl_xor(sq, m);
    }
    const float mu  = sm * (1.f / kHC);
    const float var = sq * (1.f / kHC) - mu * mu;
    const float inv = rsqrtf(var + EPS_LN);

    float y[4];
#pragma unroll
    for (int i = 0; i < 4; i++) {
        float yy = (gv[i] - mu) * inv * lnw[c4 + i] + lnb[c4 + i];
        y[i] = yy > 0.f ? yy : NEG_SLOPE * yy;
    }
    if (half == 0) {
        if constexpr (LAST) {
            *(float4*)&((float*)hout)[(size_t)n * kHC + c4] =
                make_float4(y[0], y[1], y[2], y[3]);
        } else {
            half4 hv;
            hv[0] = (_Float16)y[0]; hv[1] = (_Float16)y[1];
            hv[2] = (_Float16)y[2]; hv[3] = (_Float16)y[3];
            *(half4*)&((__half*)hout)[(size_t)n * kHC + c4] = hv;
        }
    }
}

extern "C" void kernel_launch(void* const* d_in, const int* in_sizes, int n_in,
                              void* d_out, int out_size, void* d_ws, size_t ws_size,
                              hipStream_t stream)
{
    const float* x   = (const float*)d_in[0];
    const int*   ei  = (const int*)d_in[1];
    const float* ea  = (const float*)d_in[2];
    const float* Wq  = (const float*)d_in[3];
    const float* bq  = (const float*)d_in[4];
    const float* Wk  = (const float*)d_in[5];
    const float* bk  = (const float*)d_in[6];
    const float* Wv  = (const float*)d_in[7];
    const float* bv  = (const float*)d_in[8];
    const float* We  = (const float*)d_in[9];
    const float* be  = (const float*)d_in[10];
    const float* Wsk = (const float*)d_in[11];
    const float* bsk = (const float*)d_in[12];
    const float* Wb  = (const float*)d_in[13];
    const float* lnw = (const float*)d_in[14];
    const float* lnb = (const float*)d_in[15];
    float* out = (float*)d_out;

    const int* srcI = ei;
    const int* dstI = ei + kE;

    // ---- workspace layout (~95 MB) ----
    __half* q16  = (__half*)d_ws;
    unsigned char* kv8 = (unsigned char*)(q16 + (size_t)kN * kHC);  // [n][384B]
    __half* qeW  = (__half*)(kv8 + (size_t)kN * kKVB);
    __half* xr16 = qeW + (size_t)kN * kHC;
    __half* h16  = xr16 + (size_t)kN * kHC;
    int* deg     = (int*)(h16 + (size_t)kN * kHC);
    int* rowptr  = deg + kN;
    int* cursor  = rowptr + kN + 1;
    int* esrc    = cursor + kN;
    int* eidx    = esrc + kE;
    __half* eacs = (__half*)(eidx + kE);
    _Float16* Wt = (_Float16*)(eacs + (size_t)kE * kED);   // 128 KB
    _Float16* We16 = Wt + 4 * 128 * 128;                   // 8 KB
    _Float16* Wqet = We16 + kED * kHC;                     // 32 KB
    float* bqe   = (float*)(Wqet + 128 * 128);             // 512 B
    int* locInc  = (int*)(bqe + 128);
    int* blockSum = locInc + kN;

    // ---- CSR build (edge_index constant across layers) ----
    hipMemsetAsync(deg, 0, (size_t)kN * sizeof(int), stream);
    hist_kernel<<<(kE + 255) / 256, 256, 0, stream>>>(dstI, deg);
    scanA_kernel<<<kScanB, 256, 0, stream>>>(deg, locInc, blockSum);
    scanC_kernel<<<kScanB, 256, 0, stream>>>(deg, locInc, blockSum, rowptr, cursor);
    scatter_kernel<<<(kE + 255) / 256, 256, 0, stream>>>(srcI, dstI, cursor, esrc, eidx);
    ea_csr_kernel<<<(kE * 16 + 255) / 256, 256, 0, stream>>>(ea, eidx, eacs);

    for (int l = 0; l < kL; l++) {
        prep_kernel<<<113, 256, 0, stream>>>(
            Wq + (size_t)l * kHC * kHC, Wk + (size_t)l * kHC * kHC,
            Wv + (size_t)l * kHC * kHC, Wsk + (size_t)l * kHC * kHC,
            We + (size_t)l * kED * kHC, bq + (size_t)l * kHC,
            Wt, We16, Wqet, bqe);
        if (l == 0)
            proj_mfma_kernel<false><<<kProjBlocks, 256, 0, stream>>>(
                x, Wt, Wqet,
                bq + (size_t)l * kHC, bk + (size_t)l * kHC,
                bv + (size_t)l * kHC, bsk + (size_t)l * kHC, bqe,
                (_Float16*)q16, kv8, (_Float16*)xr16, (_Float16*)qeW);
        else
            proj_mfma_kernel<true><<<kProjBlocks, 256, 0, stream>>>(
                h16, Wt, Wqet,
                bq + (size_t)l * kHC, bk + (size_t)l * kHC,
                bv + (size_t)l * kHC, bsk + (size_t)l * kHC, bqe,
                (_Float16*)q16, kv8, (_Float16*)xr16, (_Float16*)qeW);
        if (l == 0)
            node_kernel<false><<<kN / 2, 128, 0, stream>>>(
                (const _Float16*)q16, qeW, (const _Float16*)eacs,
                kv8, rowptr, esrc,
                We16, be + (size_t)l * kHC,
                xr16, Wb + (size_t)l * 3 * kHC,
                lnw + (size_t)l * kHC, lnb + (size_t)l * kHC,
                h16);
        else
            node_kernel<true><<<kN / 2, 128, 0, stream>>>(
                (const _Float16*)q16, qeW, (const _Float16*)eacs,
                kv8, rowptr, esrc,
                We16, be + (size_t)l * kHC,
                xr16, Wb + (size_t)l * 3 * kHC,
                lnw + (size_t)l * kHC, lnb + (size_t)l * kHC,
                out);
    }
}

// Round 23
// 238.841 us; speedup vs baseline: 1.2976x; 1.0602x over previous
//
#include <hip/hip_runtime.h>
#include <hip/hip_fp16.h>

constexpr int kN  = 50000;
constexpr int kE  = 400000;
constexpr int kHC = 128;
constexpr int kED = 32;
constexpr int kL  = 2;
constexpr int kScanB = (kN + 255) / 256;   // 196
constexpr int kProjBlocks = 512;           // persistent: 2 per CU
constexpr int kTiles = (kN + 31) / 32;     // 1563
constexpr int kKVB = 384;                  // bytes per kv row: 128 fp8 k + 256 fp16 v
#define EPS_LN 1e-5f
#define NEG_SLOPE 0.01f
#define RSQRT_C 0.17677669529663687f  // 1/sqrt(32)

using half8 = __attribute__((ext_vector_type(8))) _Float16;
using half4 = __attribute__((ext_vector_type(4))) _Float16;
using h2    = __attribute__((ext_vector_type(2))) _Float16;
using f32x4 = __attribute__((ext_vector_type(4))) float;

// ---------------- Fused per-layer prep: Wt | We16 | Wqet | bqe --------------
__global__ __launch_bounds__(256) void prep_kernel(
    const float* __restrict__ Wq, const float* __restrict__ Wk,
    const float* __restrict__ Wv, const float* __restrict__ Ws,
    const float* __restrict__ We, const float* __restrict__ bq,
    _Float16* __restrict__ Wt, _Float16* __restrict__ We16,
    _Float16* __restrict__ Wqet, float* __restrict__ bqe)
{
    const int b = blockIdx.x;
    const int t = threadIdx.x;
    if (b < 32) {
        const int g = b * 256 + t;          // 8192
        const int n  = g & 127;
        const int kc = (g >> 7) & 15;
        const int mat = g >> 11;
        const float* W = mat == 0 ? Wq : mat == 1 ? Wk : mat == 2 ? Wv : Ws;
        _Float16* dst = Wt + ((size_t)mat * 128 + n) * 128 + kc * 8;
#pragma unroll
        for (int i = 0; i < 8; i++) dst[i] = (_Float16)W[(kc * 8 + i) * kHC + n];
    } else if (b < 48) {
        const int g = (b - 32) * 256 + t;   // 4096
        We16[g] = (_Float16)We[g];
    } else if (b < 112) {
        const int g = (b - 48) * 256 + t;   // 16384
        const int o = g >> 7;
        const int k = g & 127;
        const int h = o >> 5;
        const int j = o & 31;
        const float* wq = Wq + k * kHC + h * 32;
        const float* we = We + j * kHC + h * 32;
        float s = 0.f;
#pragma unroll
        for (int i = 0; i < 32; i++) s = fmaf(wq[i], we[i], s);
        Wqet[o * 128 + k] = (_Float16)s;
    } else {
        if (t < 128) {
            const int o = t;
            const int h = o >> 5;
            const int j = o & 31;
            const float* bb = bq + h * 32;
            const float* we = We + j * kHC + h * 32;
            float s = 0.f;
#pragma unroll
            for (int i = 0; i < 32; i++) s = fmaf(bb[i], we[i], s);
            bqe[o] = s;
        }
    }
}

// ---------------- Persistent MFMA projection (5 outputs) --------------------
template<bool FP16IN>
__global__ __launch_bounds__(256, 2) void proj_mfma_kernel(
    const void* __restrict__ hin_, const _Float16* __restrict__ Wt,
    const _Float16* __restrict__ Wqet,
    const float* __restrict__ bq, const float* __restrict__ bk,
    const float* __restrict__ bv, const float* __restrict__ bs,
    const float* __restrict__ bqe,
    _Float16* __restrict__ q16, unsigned char* __restrict__ kv8,
    _Float16* __restrict__ xr16, _Float16* __restrict__ qeW16)
{
    __shared__ _Float16 lds_a[4096];
    __shared__ _Float16 lds_o[5][32 * 132];
    const int t = threadIdx.x;
    const int w = t >> 6;
    const int lane = t & 63;
    const int nrow = lane & 15;
    const int kc4  = (lane >> 4) * 4;

    half8 bf[32];
    {
        const _Float16* wtm = Wt + (size_t)w * 128 * 128;
#pragma unroll
        for (int ks = 0; ks < 4; ks++)
#pragma unroll
            for (int nt = 0; nt < 8; nt++)
                bf[ks * 8 + nt] = *(const half8*)
                    &wtm[(size_t)(nt * 16 + nrow) * 128 + ks * 32 + (lane >> 4) * 8];
    }

    const int sr  = t >> 3;
    const int sk0 = (t & 7) * 16;
    const int smt = sr >> 4;
    const int sl15 = sr & 15;

    float4 f[4];
    half8 hh[2];

    auto stage_to_regs = [&](int tile) {
        const int row = tile * 32 + sr;
        if (row < kN) {
            if constexpr (FP16IN) {
                const _Float16* src = (const _Float16*)hin_ + (size_t)row * kHC + sk0;
                hh[0] = *(const half8*)&src[0];
                hh[1] = *(const half8*)&src[8];
            } else {
                const float4* src = (const float4*)((const float*)hin_ + (size_t)row * kHC + sk0);
                f[0] = src[0]; f[1] = src[1]; f[2] = src[2]; f[3] = src[3];
            }
        } else {
            if constexpr (FP16IN) {
                hh[0] = half8{0, 0, 0, 0, 0, 0, 0, 0};
                hh[1] = half8{0, 0, 0, 0, 0, 0, 0, 0};
            } else {
                f[0] = f[1] = f[2] = f[3] = make_float4(0.f, 0.f, 0.f, 0.f);
            }
        }
    };

    auto regs_to_lds = [&]() {
        half8 h0, h1;
        if constexpr (FP16IN) {
            h0 = hh[0]; h1 = hh[1];
        } else {
            h0[0] = (_Float16)f[0].x; h0[1] = (_Float16)f[0].y;
            h0[2] = (_Float16)f[0].z; h0[3] = (_Float16)f[0].w;
            h0[4] = (_Float16)f[1].x; h0[5] = (_Float16)f[1].y;
            h0[6] = (_Float16)f[1].z; h0[7] = (_Float16)f[1].w;
            h1[0] = (_Float16)f[2].x; h1[1] = (_Float16)f[2].y;
            h1[2] = (_Float16)f[2].z; h1[3] = (_Float16)f[2].w;
            h1[4] = (_Float16)f[3].x; h1[5] = (_Float16)f[3].y;
            h1[6] = (_Float16)f[3].z; h1[7] = (_Float16)f[3].w;
        }
#pragma unroll
        for (int g = 0; g < 2; g++) {
            const int k  = sk0 + g * 8;
            const int ks = k >> 5;
            const int kc = (k >> 3) & 3;
            *(half8*)&lds_a[(((smt * 4 + ks) * 64) + kc * 16 + sl15) * 8] = g ? h1 : h0;
        }
    };

    const float* biasp = (w == 0) ? bq : (w == 1) ? bk : (w == 2) ? bv : bs;
    float bb[8];
#pragma unroll
    for (int nt = 0; nt < 8; nt++) bb[nt] = biasp[nt * 16 + nrow];
    float bb5[2];
#pragma unroll
    for (int u = 0; u < 2; u++) bb5[u] = bqe[(2 * w + u) * 16 + nrow];

    int tile = blockIdx.x;
    stage_to_regs(tile);

    for (;;) {
        __syncthreads();
        regs_to_lds();
        __syncthreads();

        const int next = tile + kProjBlocks;
        const bool more = next < kTiles;
        if (more) stage_to_regs(next);

        f32x4 acc[2][8];
        f32x4 acc5[2][2];
        const f32x4 z = {0.f, 0.f, 0.f, 0.f};
#pragma unroll
        for (int mt = 0; mt < 2; mt++) {
#pragma unroll
            for (int nt = 0; nt < 8; nt++) acc[mt][nt] = z;
            acc5[mt][0] = z; acc5[mt][1] = z;
        }

#pragma unroll
        for (int ks = 0; ks < 4; ks++) {
            const half8 a0 = *(const half8*)&lds_a[((0 * 4 + ks) * 64 + lane) * 8];
            const half8 a1 = *(const half8*)&lds_a[((1 * 4 + ks) * 64 + lane) * 8];
#pragma unroll
            for (int nt = 0; nt < 8; nt++) {
                acc[0][nt] = __builtin_amdgcn_mfma_f32_16x16x32_f16(a0, bf[ks * 8 + nt], acc[0][nt], 0, 0, 0);
                acc[1][nt] = __builtin_amdgcn_mfma_f32_16x16x32_f16(a1, bf[ks * 8 + nt], acc[1][nt], 0, 0, 0);
            }
#pragma unroll
            for (int u = 0; u < 2; u++) {
                const half8 b5 = *(const half8*)
                    &Wqet[(size_t)((2 * w + u) * 16 + nrow) * 128 + ks * 32 + (lane >> 4) * 8];
                acc5[0][u] = __builtin_amdgcn_mfma_f32_16x16x32_f16(a0, b5, acc5[0][u], 0, 0, 0);
                acc5[1][u] = __builtin_amdgcn_mfma_f32_16x16x32_f16(a1, b5, acc5[1][u], 0, 0, 0);
            }
        }

#pragma unroll
        for (int nt = 0; nt < 8; nt++) {
#pragma unroll
            for (int mt = 0; mt < 2; mt++)
#pragma unroll
                for (int r = 0; r < 4; r++)
                    lds_o[w][(mt * 16 + kc4 + r) * 132 + nt * 16 + nrow] =
                        (_Float16)(acc[mt][nt][r] + bb[nt]);
        }
#pragma unroll
        for (int u = 0; u < 2; u++) {
#pragma unroll
            for (int mt = 0; mt < 2; mt++)
#pragma unroll
                for (int r = 0; r < 4; r++)
                    lds_o[4][(mt * 16 + kc4 + r) * 132 + (2 * w + u) * 16 + nrow] =
                        (_Float16)(acc5[mt][u][r] + bb5[u]);
        }
        __syncthreads();

        const int grow = tile * 32 + sr;
        if (grow < kN) {
            {   // q
                const _Float16* s = &lds_o[0][sr * 132 + sk0];
                _Float16* d = q16 + (size_t)grow * kHC + sk0;
#pragma unroll
                for (int i = 0; i < 4; i++)
                    *(half4*)&d[i * 4] = *(const half4*)&s[i * 4];
            }
            {   // k fp8: row bytes [0,128)
                const _Float16* sk = &lds_o[1][sr * 132 + sk0];
                unsigned int w4[4];
#pragma unroll
                for (int p = 0; p < 4; p++) {
                    unsigned int wd = 0;
                    wd = __builtin_amdgcn_cvt_pk_fp8_f32(
                        (float)sk[4 * p], (float)sk[4 * p + 1], wd, false);
                    wd = __builtin_amdgcn_cvt_pk_fp8_f32(
                        (float)sk[4 * p + 2], (float)sk[4 * p + 3], wd, true);
                    w4[p] = wd;
                }
                *(uint4*)(kv8 + (size_t)grow * kKVB + sk0) =
                    make_uint4(w4[0], w4[1], w4[2], w4[3]);
            }
            {   // v fp16: row bytes [128,384)
                const _Float16* sv = &lds_o[2][sr * 132 + sk0];
                _Float16* d = (_Float16*)(kv8 + (size_t)grow * kKVB + 128) + sk0;
                *(half8*)&d[0] = *(const half8*)&sv[0];
                *(half8*)&d[8] = *(const half8*)&sv[8];
            }
            {   // xr
                const _Float16* s = &lds_o[3][sr * 132 + sk0];
                _Float16* d = xr16 + (size_t)grow * kHC + sk0;
#pragma unroll
                for (int i = 0; i < 4; i++)
                    *(half4*)&d[i * 4] = *(const half4*)&s[i * 4];
            }
            {   // qeW
                const _Float16* s = &lds_o[4][sr * 132 + sk0];
                _Float16* d = qeW16 + (size_t)grow * kHC + sk0;
#pragma unroll
                for (int i = 0; i < 4; i++)
                    *(half4*)&d[i * 4] = *(const half4*)&s[i * 4];
            }
        }

        if (!more) break;
        tile = next;
    }
}

// ---------------- CSR build (once per call) ---------------------------------
__global__ __launch_bounds__(256) void hist_kernel(
    const int* __restrict__ dstI, int* __restrict__ deg)
{
    const int e = blockIdx.x * 256 + threadIdx.x;
    if (e < kE) atomicAdd(&deg[dstI[e]], 1);
}

__global__ __launch_bounds__(256) void scanA_kernel(
    const int* __restrict__ deg, int* __restrict__ locInc, int* __restrict__ blockSum)
{
    __shared__ int sm[256];
    const int t = threadIdx.x;
    const int i = blockIdx.x * 256 + t;
    sm[t] = (i < kN) ? deg[i] : 0;
    __syncthreads();
    for (int off = 1; off < 256; off <<= 1) {
        const int x = (t >= off) ? sm[t - off] : 0;
        __syncthreads();
        sm[t] += x;
        __syncthreads();
    }
    if (i < kN) locInc[i] = sm[t];
    if (t == 255) blockSum[blockIdx.x] = sm[255];
}

__global__ __launch_bounds__(256) void scanC_kernel(
    const int* __restrict__ deg, const int* __restrict__ locInc,
    const int* __restrict__ blockSum,
    int* __restrict__ rowptr, int* __restrict__ cursor)
{
    __shared__ int sm[256];
    const int t = threadIdx.x;
    const int b = blockIdx.x;
    sm[t] = (t < b) ? blockSum[t] : 0;   // b <= 195 < 256
    __syncthreads();
    for (int s = 128; s > 0; s >>= 1) {
        if (t < s) sm[t] += sm[t + s];
        __syncthreads();
    }
    const int off = sm[0];
    const int i = b * 256 + t;
    if (i < kN) {
        const int inc = locInc[i];
        const int excl = off + inc - deg[i];
        rowptr[i] = excl;
        cursor[i] = excl;
        if (i == kN - 1) rowptr[kN] = off + inc;
    }
}

// ---------------- Scatter + ea->fp8 CSR copy (fused, once per call) ---------
__global__ __launch_bounds__(256) void scatter_kernel(
    const int* __restrict__ srcI, const int* __restrict__ dstI,
    const float* __restrict__ ea,
    int* __restrict__ cursor, int* __restrict__ esrc,
    unsigned char* __restrict__ eacs8)
{
    const int e = blockIdx.x * 256 + threadIdx.x;
    if (e >= kE) return;
    const int d = dstI[e];
    const int pos = atomicAdd(&cursor[d], 1);
    esrc[pos] = srcI[e];
    const float* ar = ea + (size_t)e * kED;
    unsigned int w8[8];
#pragma unroll
    for (int p = 0; p < 8; p++) {
        unsigned int wd = 0;
        wd = __builtin_amdgcn_cvt_pk_fp8_f32(ar[4 * p], ar[4 * p + 1], wd, false);
        wd = __builtin_amdgcn_cvt_pk_fp8_f32(ar[4 * p + 2], ar[4 * p + 3], wd, true);
        w8[p] = wd;
    }
    uint4* dst = (uint4*)(eacs8 + (size_t)pos * 32);
    dst[0] = make_uint4(w8[0], w8[1], w8[2], w8[3]);
    dst[1] = make_uint4(w8[4], w8[5], w8[6], w8[7]);
}

// ---------------- Fused node pass: 2 edges/wave, 4 channels/lane ------------
// lanes 0-31 = edge A, lanes 32-63 = edge B; 8-lane group = head.
#define PROCESS_PAIRS(U, PRED)                                               \
    {                                                                        \
        int idxv[U]; int sv[U];                                              \
        _Pragma("unroll")                                                    \
        for (int u = 0; u < U; u++) {                                        \
            idxv[u] = jj + 2 * u + half;                                     \
            if (PRED && idxv[u] >= endp) idxv[u] = beg;                      \
            sv[u] = esrc[idxv[u]];                                           \
        }                                                                    \
        unsigned int kw[U], ew[U]; h2 v0[U], v1[U];                          \
        _Pragma("unroll")                                                    \
        for (int u = 0; u < U; u++) {                                        \
            const unsigned char* row = kv8 + (size_t)sv[u] * kKVB;           \
            kw[u] = *(const unsigned int*)(row + c4);                        \
            const _Float16* vp = (const _Float16*)(row + 128) + c4;          \
            v0[u] = *(const h2*)vp;  v1[u] = *(const h2*)(vp + 2);           \
            ew[u] = *(const unsigned int*)(eacs8 + (size_t)idxv[u] * 32 + lg4); \
        }                                                                    \
        float p[U]; float ef[U][4];                                          \
        _Pragma("unroll")                                                    \
        for (int u = 0; u < U; u++) {                                        \
            ef[u][0] = __builtin_amdgcn_cvt_f32_fp8(ew[u], 0);               \
            ef[u][1] = __builtin_amdgcn_cvt_f32_fp8(ew[u], 1);               \
            ef[u][2] = __builtin_amdgcn_cvt_f32_fp8(ew[u], 2);               \
            ef[u][3] = __builtin_amdgcn_cvt_f32_fp8(ew[u], 3);               \
            p[u] = qf[0] * __builtin_amdgcn_cvt_f32_fp8(kw[u], 0)            \
                 + qf[1] * __builtin_amdgcn_cvt_f32_fp8(kw[u], 1)            \
                 + qf[2] * __builtin_amdgcn_cvt_f32_fp8(kw[u], 2)            \
                 + qf[3] * __builtin_amdgcn_cvt_f32_fp8(kw[u], 3);           \
            p[u] = fmaf(qwf[0], ef[u][0], p[u]);                             \
            p[u] = fmaf(qwf[1], ef[u][1], p[u]);                             \
            p[u] = fmaf(qwf[2], ef[u][2], p[u]);                             \
            p[u] = fmaf(qwf[3], ef[u][3], p[u]);                             \
        }                                                                    \
        _Pragma("unroll")                                                    \
        for (int m = 1; m <= 4; m <<= 1) {                                   \
            _Pragma("unroll")                                                \
            for (int u = 0; u < U; u++) p[u] += __shfl_xor(p[u], m);         \
        }                                                                    \
        _Pragma("unroll")                                                    \
        for (int u = 0; u < U; u++) {                                        \
            float a = __expf((p[u] + qbv) * RSQRT_C);                        \
            if (PRED && (jj + 2 * u + half >= endp)) a = 0.f;                \
            den += a;                                                        \
            acc[0] = fmaf((float)v0[u][0], a, acc[0]);                       \
            acc[1] = fmaf((float)v0[u][1], a, acc[1]);                       \
            acc[2] = fmaf((float)v1[u][0], a, acc[2]);                       \
            acc[3] = fmaf((float)v1[u][1], a, acc[3]);                       \
            t4[0] = fmaf(ef[u][0], a, t4[0]);                                \
            t4[1] = fmaf(ef[u][1], a, t4[1]);                                \
            t4[2] = fmaf(ef[u][2], a, t4[2]);                                \
            t4[3] = fmaf(ef[u][3], a, t4[3]);                                \
        }                                                                    \
    }

template<bool LAST>
__global__ __launch_bounds__(128) void node_kernel(
    const _Float16* __restrict__ q16, const __half* __restrict__ qeW,
    const unsigned char* __restrict__ eacs8,
    const unsigned char* __restrict__ kv8,
    const int* __restrict__ rowptr, const int* __restrict__ esrc,
    const _Float16* __restrict__ We16, const float* __restrict__ be,
    const __half* __restrict__ xr16, const float* __restrict__ Wb,
    const float* __restrict__ lnw, const float* __restrict__ lnb,
    void* __restrict__ hout)
{
    __shared__ __half wes[kED * kHC];   // 8 KB
    const int t = threadIdx.x;
    {
        float4* d4 = (float4*)wes;
        const float4* s4 = (const float4*)We16;
#pragma unroll
        for (int i = 0; i < 4; i++) d4[t + 128 * i] = s4[t + 128 * i];
    }
    __syncthreads();

    const int n = blockIdx.x * 2 + (t >> 6);   // kN % 2 == 0
    const int lane = t & 63;
    const int hl   = lane & 31;
    const int half = lane >> 5;
    const int hd   = hl >> 3;
    const int lg   = hl & 7;
    const int c4   = hd * 32 + lg * 4;
    const int lg4  = lg * 4;

    float qf[4], qwf[4];
    {
        const h2 qa = *(const h2*)&q16[n * kHC + c4];
        const h2 qbx = *(const h2*)&q16[n * kHC + c4 + 2];
        qf[0] = (float)qa[0];  qf[1] = (float)qa[1];
        qf[2] = (float)qbx[0]; qf[3] = (float)qbx[1];
        const _Float16* qw = (const _Float16*)qeW + n * kHC + c4;
        const h2 qw0 = *(const h2*)qw;
        const h2 qw1 = *(const h2*)(qw + 2);
        qwf[0] = (float)qw0[0]; qwf[1] = (float)qw0[1];
        qwf[2] = (float)qw1[0]; qwf[3] = (float)qw1[1];
    }
    float qbv;
    {
        const float4 bev = *(const float4*)&be[c4];
        qbv = qf[0] * bev.x + qf[1] * bev.y + qf[2] * bev.z + qf[3] * bev.w;
#pragma unroll
        for (int m = 1; m <= 4; m <<= 1) qbv += __shfl_xor(qbv, m);
    }

    float acc[4] = {0.f, 0.f, 0.f, 0.f};
    float t4[4]  = {0.f, 0.f, 0.f, 0.f};
    float den = 0.f;
    const int beg = rowptr[n], endp = rowptr[n + 1];

    int jj = beg;
    for (; jj + 8 <= endp; jj += 8) PROCESS_PAIRS(4, 0)
    for (; jj + 4 <= endp; jj += 4) PROCESS_PAIRS(2, 0)
    for (; jj < endp; jj += 2)      PROCESS_PAIRS(1, 1)

    den += __shfl_xor(den, 32);
#pragma unroll
    for (int i = 0; i < 4; i++) {
        acc[i] += __shfl_xor(acc[i], 32);
        t4[i]  += __shfl_xor(t4[i], 32);
    }

    const float invd = 1.f / (den + 1e-16f);
    float o[4], tn[4];
#pragma unroll
    for (int i = 0; i < 4; i++) { o[i] = acc[i] * invd; tn[i] = t4[i] * invd; }

    const int gb = (lane & 32) | (hd * 8);
#pragma unroll
    for (int jo = 0; jo < 8; jo++) {
        float Tv[4];
#pragma unroll
        for (int ji = 0; ji < 4; ji++) Tv[ji] = __shfl(tn[ji], gb | jo);
#pragma unroll
        for (int ji = 0; ji < 4; ji++) {
            const int j = jo * 4 + ji;
            const float2 wA = __half22float2(*(const __half2*)&wes[j * kHC + c4]);
            const float2 wB = __half22float2(*(const __half2*)&wes[j * kHC + c4 + 2]);
            o[0] = fmaf(Tv[ji], wA.x, o[0]);
            o[1] = fmaf(Tv[ji], wA.y, o[1]);
            o[2] = fmaf(Tv[ji], wB.x, o[2]);
            o[3] = fmaf(Tv[ji], wB.y, o[3]);
        }
    }
#pragma unroll
    for (int i = 0; i < 4; i++) o[i] += be[c4 + i];

    float r[4];
    {
        const float2 rA = __half22float2(*(const __half2*)&xr16[(size_t)n * kHC + c4]);
        const float2 rB = __half22float2(*(const __half2*)&xr16[(size_t)n * kHC + c4 + 2]);
        r[0] = rA.x; r[1] = rA.y; r[2] = rB.x; r[3] = rB.y;
    }
    float z = 0.f;
#pragma unroll
    for (int i = 0; i < 4; i++) {
        z += o[i] * Wb[c4 + i] + r[i] * Wb[kHC + c4 + i]
           + (o[i] - r[i]) * Wb[2 * kHC + c4 + i];
    }
#pragma unroll
    for (int m = 1; m < 32; m <<= 1) z += __shfl_xor(z, m);
    const float beta = 1.f / (1.f + __expf(-z));

    float gv[4];
    float sm = 0.f, sq = 0.f;
#pragma unroll
    for (int i = 0; i < 4; i++) {
        gv[i] = beta * r[i] + (1.f - beta) * o[i];
        sm += gv[i];
        sq += gv[i] * gv[i];
    }
#pragma unroll
    for (int m = 1; m < 32; m <<= 1) {
        sm += __shfl_xor(sm, m);
        sq += __shfl_xor(sq, m);
    }
    const float mu  = sm * (1.f / kHC);
    const float var = sq * (1.f / kHC) - mu * mu;
    const float inv = rsqrtf(var + EPS_LN);

    float y[4];
#pragma unroll
    for (int i = 0; i < 4; i++) {
        float yy = (gv[i] - mu) * inv * lnw[c4 + i] + lnb[c4 + i];
        y[i] = yy > 0.f ? yy : NEG_SLOPE * yy;
    }
    if (half == 0) {
        if constexpr (LAST) {
            *(float4*)&((float*)hout)[(size_t)n * kHC + c4] =
                make_float4(y[0], y[1], y[2], y[3]);
        } else {
            half4 hv;
            hv[0] = (_Float16)y[0]; hv[1] = (_Float16)y[1];
            hv[2] = (_Float16)y[2]; hv[3] = (_Float16)y[3];
            *(half4*)&((__half*)hout)[(size_t)n * kHC + c4] = hv;
        }
    }
}

extern "C" void kernel_launch(void* const* d_in, const int* in_sizes, int n_in,
                              void* d_out, int out_size, void* d_ws, size_t ws_size,
                              hipStream_t stream)
{
    const float* x   = (const float*)d_in[0];
    const int*   ei  = (const int*)d_in[1];
    const float* ea  = (const float*)d_in[2];
    const float* Wq  = (const float*)d_in[3];
    const float* bq  = (const float*)d_in[4];
    const float* Wk  = (const float*)d_in[5];
    const float* bk  = (const float*)d_in[6];
    const float* Wv  = (const float*)d_in[7];
    const float* bv  = (const float*)d_in[8];
    const float* We  = (const float*)d_in[9];
    const float* be  = (const float*)d_in[10];
    const float* Wsk = (const float*)d_in[11];
    const float* bsk = (const float*)d_in[12];
    const float* Wb  = (const float*)d_in[13];
    const float* lnw = (const float*)d_in[14];
    const float* lnb = (const float*)d_in[15];
    float* out = (float*)d_out;

    const int* srcI = ei;
    const int* dstI = ei + kE;

    // ---- workspace layout (~80 MB) ----
    __half* q16  = (__half*)d_ws;
    unsigned char* kv8 = (unsigned char*)(q16 + (size_t)kN * kHC);  // [n][384B]
    __half* qeW  = (__half*)(kv8 + (size_t)kN * kKVB);
    __half* xr16 = qeW + (size_t)kN * kHC;
    __half* h16  = xr16 + (size_t)kN * kHC;
    int* deg     = (int*)(h16 + (size_t)kN * kHC);
    int* rowptr  = deg + kN;
    int* cursor  = rowptr + kN + 1;
    int* esrc    = cursor + kN;
    unsigned char* eacs8 = (unsigned char*)(esrc + kE);   // [E][32B] fp8
    _Float16* Wt = (_Float16*)(eacs8 + (size_t)kE * 32);  // 128 KB
    _Float16* We16 = Wt + 4 * 128 * 128;                  // 8 KB
    _Float16* Wqet = We16 + kED * kHC;                    // 32 KB
    float* bqe   = (float*)(Wqet + 128 * 128);            // 512 B
    int* locInc  = (int*)(bqe + 128);
    int* blockSum = locInc + kN;

    // ---- CSR build (edge_index constant across layers) ----
    hipMemsetAsync(deg, 0, (size_t)kN * sizeof(int), stream);
    hist_kernel<<<(kE + 255) / 256, 256, 0, stream>>>(dstI, deg);
    scanA_kernel<<<kScanB, 256, 0, stream>>>(deg, locInc, blockSum);
    scanC_kernel<<<kScanB, 256, 0, stream>>>(deg, locInc, blockSum, rowptr, cursor);
    scatter_kernel<<<(kE + 255) / 256, 256, 0, stream>>>(srcI, dstI, ea,
                                                         cursor, esrc, eacs8);

    for (int l = 0; l < kL; l++) {
        prep_kernel<<<113, 256, 0, stream>>>(
            Wq + (size_t)l * kHC * kHC, Wk + (size_t)l * kHC * kHC,
            Wv + (size_t)l * kHC * kHC, Wsk + (size_t)l * kHC * kHC,
            We + (size_t)l * kED * kHC, bq + (size_t)l * kHC,
            Wt, We16, Wqet, bqe);
        if (l == 0)
            proj_mfma_kernel<false><<<kProjBlocks, 256, 0, stream>>>(
                x, Wt, Wqet,
                bq + (size_t)l * kHC, bk + (size_t)l * kHC,
                bv + (size_t)l * kHC, bsk + (size_t)l * kHC, bqe,
                (_Float16*)q16, kv8, (_Float16*)xr16, (_Float16*)qeW);
        else
            proj_mfma_kernel<true><<<kProjBlocks, 256, 0, stream>>>(
                h16, Wt, Wqet,
                bq + (size_t)l * kHC, bk + (size_t)l * kHC,
                bv + (size_t)l * kHC, bsk + (size_t)l * kHC, bqe,
                (_Float16*)q16, kv8, (_Float16*)xr16, (_Float16*)qeW);
        if (l == 0)
            node_kernel<false><<<kN / 2, 128, 0, stream>>>(
                (const _Float16*)q16, qeW, eacs8,
                kv8, rowptr, esrc,
                We16, be + (size_t)l * kHC,
                xr16, Wb + (size_t)l * 3 * kHC,
                lnw + (size_t)l * kHC, lnb + (size_t)l * kHC,
                h16);
        else
            node_kernel<true><<<kN / 2, 128, 0, stream>>>(
                (const _Float16*)q16, qeW, eacs8,
                kv8, rowptr, esrc,
                We16, be + (size_t)l * kHC,
                xr16, Wb + (size_t)l * 3 * kHC,
                lnw + (size_t)l * kHC, lnb + (size_t)l * kHC,
                out);
    }
}